// Round 3
// baseline (234.342 us; speedup 1.0000x reference)
//
#include <hip/hip_runtime.h>
#include <math.h>

// FourierCrossAttention: B=16, L=S=2048, H=8, E=O=64, M=64 (first 64 rfft modes)
// Pipeline: tables -> MFMA split-bf16 DFT(q,k,v) [K-split x2 + reduce] -> QK+tanh
//           -> QKV -> Wt -> QKVW -> iDFT
// DFT uses 3-product hi/lo bf16 split (XhTh + XhTl + XlTh) for fp32-grade accuracy.

#define NB 16
#define NL 2048
#define NH 8
#define NE 64
#define NM 64
#define NHE 512  // H*E

typedef unsigned short ushort_t;
typedef __attribute__((ext_vector_type(8))) short short8;
typedef __attribute__((ext_vector_type(4))) float f32x4;

// table layout: [64 ksteps][128 m'][32 shorts] (unpadded; 8192 B per kstep per table)
#define TW_ELEMS (64 * 128 * 32)

__device__ inline void gld_lds16(const void* g, void* l) {
    __builtin_amdgcn_global_load_lds((const __attribute__((address_space(1))) unsigned int*)g,
                                     (__attribute__((address_space(3))) unsigned int*)l, 16, 0, 0);
}

// ---------------- K0a: bf16 hi/lo twiddle tables (unpadded staging layout) ----------------
__global__ __launch_bounds__(256) void k_tables_gemm(ushort_t* __restrict__ Twh,
                                                     ushort_t* __restrict__ Twl) {
    int i = blockIdx.x * 256 + threadIdx.x;  // over 64*128*32 = 262144
    int s = i & 31;
    int mp = (i >> 5) & 127;
    int ks = i >> 12;
    int t = ks * 32 + s;
    int m = mp >> 1;
    float ang = (float)((6.283185307179586476925287 / (double)NL) * (double)((m * t) & (NL - 1)));
    float sv, cv;
    __sincosf(ang, &sv, &cv);
    // __sincosf is fast-math-grade; use precise versions:
    sv = sinf(ang);
    cv = cosf(ang);
    float cf = (mp & 1) ? -sv : cv;
    unsigned cb = __float_as_uint(cf);
    unsigned hb = cb & 0xffff0000u;
    ushort_t h = (ushort_t)(cb >> 16);
    float lo = cf - __uint_as_float(hb);
    unsigned lb = __float_as_uint(lo);
    unsigned r = lb + 0x7fffu + ((lb >> 16) & 1u);
    ushort_t l = (ushort_t)(r >> 16);
    Twh[i] = h;
    Twl[i] = l;
}

// ---------------- K0b: fp32 iDFT table TabT[m][t] = (cos, -sin) ----------------
__global__ __launch_bounds__(256) void k_tabT(float2* __restrict__ TabT) {
    int i = blockIdx.x * 256 + threadIdx.x;  // over M*L = 131072
    int t = i >> 6, m = i & 63;
    float ang = (float)((6.283185307179586476925287 / (double)NL) * (double)((t * m) & (NL - 1)));
    TabT[(size_t)m * NL + t] = make_float2(cosf(ang), -sinf(ang));
}

// ---------------- K1: MFMA DFT, K-split x2 ----------------
// Cpart[he, m'] = sum_{t in half kq} X[t, he] * Tw[t, m'], per (b, z, kq).
// Block: 64 he x 128 m', BK=32, 32 K-steps, A single-buffered (2 barriers), B double-buffered.
__global__ __launch_bounds__(256, 3) void k_gemm(
    const float* __restrict__ q, const float* __restrict__ k, const float* __restrict__ v,
    const ushort_t* __restrict__ Twh, const ushort_t* __restrict__ Twl,
    float* __restrict__ Part) {
    const int bx = blockIdx.x & 7;   // he-group 0..7
    const int kq = blockIdx.x >> 3;  // K-half 0..1
    const int b  = blockIdx.y;       // 0..15
    const int z  = blockIdx.z;       // 0..2
    const float* __restrict__ in = (z == 0) ? q : ((z == 1) ? k : v);

    const int tid  = threadIdx.x;
    const int wid  = tid >> 6;
    const int lane = tid & 63;
    const int lr   = lane & 15;
    const int lg   = lane >> 4;
    const int wy   = wid >> 1;  // he-half (0..1) -> +32
    const int wx   = wid & 1;   // m-half  (0..1) -> +64
    const int he0  = bx * 64;

    __shared__ float    As[32 * 67];      // 8576 B
    __shared__ ushort_t Bh[2][128 * 32];  // 16384 B
    __shared__ ushort_t Bl[2][128 * 32];  // 16384 B

    // staging thread mapping (A): idx = tid + r*256 -> he4 = idx&15, tt = idx>>4
    const int he4a = tid & 15;
    const int tt0  = tid >> 4;        // r=0: tt = tt0 ; r=1: tt = tt0 + 16
    const size_t in_row_base = ((size_t)b * NL + kq * 1024) * NHE + he0 + he4a * 4;

    f32x4 acc[2][4];
#pragma unroll
    for (int f = 0; f < 2; ++f)
#pragma unroll
        for (int j = 0; j < 4; ++j) acc[f][j] = (f32x4){0.f, 0.f, 0.f, 0.f};

    // ---- prologue: stage kstep 0 ----
    {
        const int gks = kq * 32;
        const ushort_t* gh = Twh + (size_t)gks * 4096;
        const ushort_t* gl = Twl + (size_t)gks * 4096;
        gld_lds16(gh + (size_t)tid * 8, &Bh[0][tid * 8]);
        gld_lds16(gh + (size_t)(tid + 256) * 8, &Bh[0][(tid + 256) * 8]);
        gld_lds16(gl + (size_t)tid * 8, &Bl[0][tid * 8]);
        gld_lds16(gl + (size_t)(tid + 256) * 8, &Bl[0][(tid + 256) * 8]);
        float4 av0 = *(const float4*)(in + in_row_base + (size_t)tt0 * NHE);
        float4 av1 = *(const float4*)(in + in_row_base + (size_t)(tt0 + 16) * NHE);
        float* d0 = &As[tt0 * 67 + he4a * 4];
        d0[0] = av0.x; d0[1] = av0.y; d0[2] = av0.z; d0[3] = av0.w;
        float* d1 = &As[(tt0 + 16) * 67 + he4a * 4];
        d1[0] = av1.x; d1[1] = av1.y; d1[2] = av1.z; d1[3] = av1.w;
    }

    int cur = 0;
    for (int ks = 0; ks < 32; ++ks) {
        __syncthreads();  // As ready; B[cur] gld_lds drained
        const bool more = (ks + 1) < 32;
        float4 av0, av1;
        if (more) {
            const int gks = kq * 32 + ks + 1;
            const ushort_t* gh = Twh + (size_t)gks * 4096;
            const ushort_t* gl = Twl + (size_t)gks * 4096;
            ushort_t* lbh = &Bh[cur ^ 1][0];
            ushort_t* lbl = &Bl[cur ^ 1][0];
            gld_lds16(gh + (size_t)tid * 8, lbh + tid * 8);
            gld_lds16(gh + (size_t)(tid + 256) * 8, lbh + (tid + 256) * 8);
            gld_lds16(gl + (size_t)tid * 8, lbl + tid * 8);
            gld_lds16(gl + (size_t)(tid + 256) * 8, lbl + (tid + 256) * 8);
            const size_t tb = (size_t)(ks + 1) * 32;
            av0 = *(const float4*)(in + in_row_base + (tb + tt0) * NHE);
            av1 = *(const float4*)(in + in_row_base + (tb + tt0 + 16) * NHE);
        }

        // ---- compute on As + B[cur] ----
        const ushort_t* bhc = &Bh[cur][0];
        const ushort_t* blc = &Bl[cur][0];

        short8 ah[2], al[2];
#pragma unroll
        for (int f = 0; f < 2; ++f) {
            const int he = wy * 32 + f * 16 + lr;
            float xa[8];
#pragma unroll
            for (int j = 0; j < 8; ++j) xa[j] = As[(8 * lg + j) * 67 + he];
            union { unsigned u[4]; short8 s; } uh, ul;
#pragma unroll
            for (int p = 0; p < 4; ++p) {
                unsigned b0 = __float_as_uint(xa[2 * p]);
                unsigned b1 = __float_as_uint(xa[2 * p + 1]);
                uh.u[p] = (b0 >> 16) | (b1 & 0xffff0000u);
                float l0 = xa[2 * p]     - __uint_as_float(b0 & 0xffff0000u);
                float l1 = xa[2 * p + 1] - __uint_as_float(b1 & 0xffff0000u);
                unsigned lw;
                asm("v_cvt_pk_bf16_f32 %0, %1, %2" : "=v"(lw) : "v"(l0), "v"(l1));
                ul.u[p] = lw;
            }
            ah[f] = uh.s;
            al[f] = ul.s;
        }

        short8 bh8[4], bl8[4];
#pragma unroll
        for (int j = 0; j < 4; ++j) {
            const int mp = wx * 64 + j * 16 + lr;
            bh8[j] = *(const short8*)&bhc[mp * 32 + 8 * lg];
            bl8[j] = *(const short8*)&blc[mp * 32 + 8 * lg];
        }

#pragma unroll
        for (int f = 0; f < 2; ++f) {
#pragma unroll
            for (int j = 0; j < 4; ++j) {
                acc[f][j] = __builtin_amdgcn_mfma_f32_16x16x32_bf16(ah[f], bh8[j], acc[f][j], 0, 0, 0);
                acc[f][j] = __builtin_amdgcn_mfma_f32_16x16x32_bf16(ah[f], bl8[j], acc[f][j], 0, 0, 0);
                acc[f][j] = __builtin_amdgcn_mfma_f32_16x16x32_bf16(al[f], bh8[j], acc[f][j], 0, 0, 0);
            }
        }

        __syncthreads();  // all reads of As done
        if (more) {
            float* d0 = &As[tt0 * 67 + he4a * 4];
            d0[0] = av0.x; d0[1] = av0.y; d0[2] = av0.z; d0[3] = av0.w;
            float* d1 = &As[(tt0 + 16) * 67 + he4a * 4];
            d1[0] = av1.x; d1[1] = av1.y; d1[2] = av1.z; d1[3] = av1.w;
        }
        cur ^= 1;
    }

    // ---- epilogue: Part[(z*2+kq)][(b*512+he)][m'] ----
    float* pout = Part + (size_t)(z * 2 + kq) * 1048576;
#pragma unroll
    for (int f = 0; f < 2; ++f) {
#pragma unroll
        for (int j = 0; j < 4; ++j) {
            const int col = wx * 64 + j * 16 + lr;
#pragma unroll
            for (int r = 0; r < 4; ++r) {
                const int he = he0 + wy * 32 + f * 16 + 4 * lg + r;
                pout[((size_t)b * NHE + he) * 128 + col] = acc[f][j][r];
            }
        }
    }
}

// ---------------- K1b: reduce 2 K-half partials -> Qf/Kf/Vf ----------------
__global__ __launch_bounds__(256) void k_reduce(
    const float4* __restrict__ Part, float4* __restrict__ Qf,
    float4* __restrict__ Kf, float4* __restrict__ Vf) {
    int i = blockIdx.x * 256 + threadIdx.x;  // over 3*262144
    int z = i >> 18;
    int r = i & 262143;
    float4 a = Part[(size_t)(z * 2 + 0) * 262144 + r];
    float4 b = Part[(size_t)(z * 2 + 1) * 262144 + r];
    float4 s = make_float4(a.x + b.x, a.y + b.y, a.z + b.z, a.w + b.w);
    float4* o = (z == 0) ? Qf : ((z == 1) ? Kf : Vf);
    o[r] = s;
}

// ---------------- K2: QK = sum_e Qf[e,x]*Kf[e,y]; tanh re/im ----------------
__global__ __launch_bounds__(256) void k_qk(
    const float2* __restrict__ Qf, const float2* __restrict__ Kf,
    float2* __restrict__ QKt) {
    const int bh = blockIdx.x;  // 0..127
    const int xh = blockIdx.y;  // 0..1
    const int tid = threadIdx.x;
    __shared__ float2 Qs[64 * 34];
    __shared__ float2 Ks[64 * 66];

    const float2* Qbase = Qf + (size_t)bh * (NE * NM);
    const float2* Kbase = Kf + (size_t)bh * (NE * NM);
#pragma unroll
    for (int j = 0; j < 4; ++j) {
        int n = tid + j * 256;  // 1024 f4
        int e = n >> 4, c = n & 15;
        float4 val = ((const float4*)(Qbase + e * NM + xh * 32))[c];
        *((float4*)&Qs[e * 34 + c * 2]) = val;
    }
#pragma unroll
    for (int j = 0; j < 8; ++j) {
        int n = tid + j * 256;  // 2048 f4
        int e = n >> 5, c = n & 31;
        float4 val = ((const float4*)(Kbase + e * NM))[c];
        *((float4*)&Ks[e * 66 + c * 2]) = val;
    }
    __syncthreads();

    const int yq = tid & 31, xq = tid >> 5;  // y0=2yq, x0=4xq
    float accr[4][2], acci[4][2];
#pragma unroll
    for (int i = 0; i < 4; ++i)
#pragma unroll
        for (int j = 0; j < 2; ++j) { accr[i][j] = 0.f; acci[i][j] = 0.f; }

    for (int e = 0; e < 64; ++e) {
        float4 qa = *((float4*)&Qs[e * 34 + xq * 4]);
        float4 qb = *((float4*)&Qs[e * 34 + xq * 4 + 2]);
        float4 kk = *((float4*)&Ks[e * 66 + yq * 2]);
        float qr[4] = {qa.x, qa.z, qb.x, qb.z};
        float qi[4] = {qa.y, qa.w, qb.y, qb.w};
        float kr[2] = {kk.x, kk.z};
        float ki[2] = {kk.y, kk.w};
#pragma unroll
        for (int i = 0; i < 4; ++i) {
#pragma unroll
            for (int j = 0; j < 2; ++j) {
                accr[i][j] += qr[i] * kr[j] - qi[i] * ki[j];
                acci[i][j] += qr[i] * ki[j] + qi[i] * kr[j];
            }
        }
    }
    const int x0 = xh * 32 + xq * 4;
#pragma unroll
    for (int i = 0; i < 4; ++i) {
        float4 sv = make_float4(tanhf(accr[i][0]), tanhf(acci[i][0]),
                                tanhf(accr[i][1]), tanhf(acci[i][1]));
        *((float4*)&QKt[(size_t)bh * 4096 + (x0 + i) * 64 + yq * 2]) = sv;
    }
}

// ---------------- K3: QKV[e,x] = sum_y Vf[e,y]*QKt[x,y] ----------------
__global__ __launch_bounds__(256) void k_qkv(
    const float2* __restrict__ Vf, const float2* __restrict__ QKt,
    float2* __restrict__ QKV) {
    const int bh = blockIdx.x;
    const int eh = blockIdx.y;
    const int tid = threadIdx.x;
    __shared__ float2 Vs[32 * 66];
    __shared__ float2 Ps[64 * 66];

    const float2* Vbase = Vf + (size_t)bh * (NE * NM) + eh * 32 * NM;
    const float2* Pbase = QKt + (size_t)bh * 4096;
#pragma unroll
    for (int j = 0; j < 4; ++j) {
        int n = tid + j * 256;  // 1024 f4
        int r = n >> 5, c = n & 31;
        float4 val = ((const float4*)(Vbase + r * NM))[c];
        *((float4*)&Vs[r * 66 + c * 2]) = val;
    }
#pragma unroll
    for (int j = 0; j < 8; ++j) {
        int n = tid + j * 256;
        int r = n >> 5, c = n & 31;
        float4 val = ((const float4*)(Pbase + r * NM))[c];
        *((float4*)&Ps[r * 66 + c * 2]) = val;
    }
    __syncthreads();

    const int xq = tid & 15, eq2 = tid >> 4;
    const int x0 = xq * 4, e0 = eq2 * 2;
    float accr[2][4], acci[2][4];
#pragma unroll
    for (int i = 0; i < 2; ++i)
#pragma unroll
        for (int j = 0; j < 4; ++j) { accr[i][j] = 0.f; acci[i][j] = 0.f; }

    for (int yy = 0; yy < 64; ++yy) {
        float2 v0 = Vs[(e0 + 0) * 66 + yy];
        float2 v1 = Vs[(e0 + 1) * 66 + yy];
        float2 p0 = Ps[(x0 + 0) * 66 + yy];
        float2 p1 = Ps[(x0 + 1) * 66 + yy];
        float2 p2 = Ps[(x0 + 2) * 66 + yy];
        float2 p3 = Ps[(x0 + 3) * 66 + yy];
        float pr[4] = {p0.x, p1.x, p2.x, p3.x};
        float pi[4] = {p0.y, p1.y, p2.y, p3.y};
#pragma unroll
        for (int j = 0; j < 4; ++j) {
            accr[0][j] += v0.x * pr[j] - v0.y * pi[j];
            acci[0][j] += v0.x * pi[j] + v0.y * pr[j];
            accr[1][j] += v1.x * pr[j] - v1.y * pi[j];
            acci[1][j] += v1.x * pi[j] + v1.y * pr[j];
        }
    }
#pragma unroll
    for (int e = 0; e < 2; ++e) {
        float2* obase = QKV + (size_t)bh * 4096 + (eh * 32 + e0 + e) * 64 + x0;
        float4 s0 = make_float4(accr[e][0], acci[e][0], accr[e][1], acci[e][1]);
        float4 s1 = make_float4(accr[e][2], acci[e][2], accr[e][3], acci[e][3]);
        ((float4*)obase)[0] = s0;
        ((float4*)obase)[1] = s1;
    }
}

// ---------------- K4a: transpose W -> Wt[h][x][e][o] ----------------
__global__ __launch_bounds__(256) void k_wt(
    const float* __restrict__ wr, const float* __restrict__ wi,
    float2* __restrict__ Wt) {
    const int e = blockIdx.x, h = blockIdx.y;
    const int tid = threadIdx.x;
    __shared__ float lr[64 * 68];
    __shared__ float li[64 * 68];
    const float* rbase = wr + (size_t)(h * NE + e) * NE * NM;  // [o][x]
    const float* ibase = wi + (size_t)(h * NE + e) * NE * NM;
#pragma unroll
    for (int j = 0; j < 4; ++j) {
        int n = tid + j * 256;  // 1024 f4
        int o = n >> 4, x4 = n & 15;
        float4 r4 = ((const float4*)(rbase + o * NM))[x4];
        float4 i4 = ((const float4*)(ibase + o * NM))[x4];
        *((float4*)&lr[o * 68 + x4 * 4]) = r4;
        *((float4*)&li[o * 68 + x4 * 4]) = i4;
    }
    __syncthreads();
#pragma unroll
    for (int j = 0; j < 16; ++j) {
        int n = tid + j * 256;  // 4096 outputs
        int x = n >> 6, o = n & 63;
        Wt[((size_t)(h * NM + x) * NE + e) * NE + o] =
            make_float2(lr[o * 68 + x], li[o * 68 + x]);
    }
}

// ---------------- K4: QKVW[o,x] = sum_e QKV[e,x]*W[e,o,x], scaled for irfft ----------------
__global__ __launch_bounds__(256) void k_qkvw(
    const float2* __restrict__ QKV, const float2* __restrict__ Wt,
    float2* __restrict__ QKVWs) {
    const int x = blockIdx.x, h = blockIdx.y;
    const int tid = threadIdx.x;
    const int o = tid & 63, bq = tid >> 6;
    float accr[4], acci[4];
#pragma unroll
    for (int j = 0; j < 4; ++j) { accr[j] = 0.f; acci[j] = 0.f; }

    const float2* wbase = Wt + (size_t)(h * NM + x) * NE * NE + o;
    for (int e = 0; e < 64; ++e) {
        float2 w = wbase[(size_t)e * NE];
#pragma unroll
        for (int j = 0; j < 4; ++j) {
            int b = bq * 4 + j;
            float2 a = QKV[((size_t)(b * NH + h) * NE + e) * NM + x];
            accr[j] += a.x * w.x - a.y * w.y;
            acci[j] += a.x * w.y + a.y * w.x;
        }
    }
    const float sc = (x == 0) ? (1.f / NL) : (2.f / NL);
#pragma unroll
    for (int j = 0; j < 4; ++j) {
        int b = bq * 4 + j;
        QKVWs[((size_t)(b * NH + h) * NM + x) * NE + o] =
            make_float2(accr[j] * sc, acci[j] * sc);
    }
}

// ---------------- K5: iDFT + transpose to [B,L,H,O] ----------------
__global__ __launch_bounds__(256) void k_idft(
    const float2* __restrict__ QKVWs, const float2* __restrict__ TabT,
    float* __restrict__ yout) {
    const int tt = blockIdx.x;   // 0..31
    const int bh = blockIdx.y;   // 0..127
    const int b = bh >> 3, h = bh & 7;
    const int tid = threadIdx.x;
    const int t0 = tt * 64;
    __shared__ float2 Xs[64 * 66];  // [x][o]

#pragma unroll
    for (int j = 0; j < 8; ++j) {
        int n = tid + j * 256;  // 2048 f4
        int xr = n >> 5, c = n & 31;
        float4 v4 = ((const float4*)(QKVWs + (size_t)bh * 4096 + xr * 64))[c];
        *((float4*)&Xs[xr * 66 + c * 2]) = v4;
    }
    __syncthreads();

    const int to = tid & 15, tq = tid >> 4;
    const int o0 = to * 4, tl0 = tq * 4;
    float accv[4][4];
#pragma unroll
    for (int i = 0; i < 4; ++i)
#pragma unroll
        for (int j = 0; j < 4; ++j) accv[i][j] = 0.f;

    const float4* tab4 = (const float4*)TabT;  // row x: 1024 f4
    for (int x = 0; x < 64; ++x) {
        float4 ta = tab4[(size_t)x * 1024 + (t0 + tl0) / 2];
        float4 tb = tab4[(size_t)x * 1024 + (t0 + tl0) / 2 + 1];
        float4 xa = *((float4*)&Xs[x * 66 + o0]);
        float4 xb = *((float4*)&Xs[x * 66 + o0 + 2]);
        float xrr[4] = {xa.x, xa.z, xb.x, xb.z};
        float xii[4] = {xa.y, xa.w, xb.y, xb.w};
        float tc[8] = {ta.x, ta.y, ta.z, ta.w, tb.x, tb.y, tb.z, tb.w};
#pragma unroll
        for (int it = 0; it < 4; ++it) {
            float c = tc[it * 2 + 0];
            float ns = tc[it * 2 + 1];  // = -sin
#pragma unroll
            for (int io = 0; io < 4; ++io) {
                accv[it][io] += c * xrr[io] + ns * xii[io];
            }
        }
    }
#pragma unroll
    for (int it = 0; it < 4; ++it) {
        int t = t0 + tl0 + it;
        float4 st = make_float4(accv[it][0], accv[it][1], accv[it][2], accv[it][3]);
        *((float4*)(yout + (((size_t)b * NL + t) * NH + h) * NE + o0)) = st;
    }
}

extern "C" void kernel_launch(void* const* d_in, const int* in_sizes, int n_in,
                              void* d_out, int out_size, void* d_ws, size_t ws_size,
                              hipStream_t stream) {
    const float* q  = (const float*)d_in[0];
    const float* k  = (const float*)d_in[1];
    const float* v  = (const float*)d_in[2];
    const float* wr = (const float*)d_in[3];
    const float* wi = (const float*)d_in[4];
    float* out = (float*)d_out;

    // workspace layout (bytes); Part overlays the post-reduce tail (QKt/QKV/Wt)
    char* w = (char*)d_ws;
    ushort_t* Twh  = (ushort_t*)w;                      //   524,288 B
    ushort_t* Twl  = (ushort_t*)(w + 524288);           //   524,288 B
    float2*   TabT = (float2*)(w + 1048576);            // 1,048,576 B
    float2*   Qf   = (float2*)(w + 2097152);            // 4,194,304 B each below
    float2*   Kf   = (float2*)(w + 6291456);
    float2*   Vf   = (float2*)(w + 10485760);
    float*    Part = (float*)(w + 14680064);            // 25,165,824 B (6 x 1M floats)
    float2*   QKt  = (float2*)(w + 14680064);           // overlays Part (post-reduce)
    float2*   QKV  = (float2*)(w + 18874368);
    float2*   Wt   = (float2*)(w + 23068672);           // 16,777,216 B
    float2*   QKVWs= (float2*)(w + 39845888);           // 4,194,304 B
    // total = 44,040,192 B

    hipLaunchKernelGGL(k_tables_gemm, dim3(1024), dim3(256), 0, stream, Twh, Twl);
    hipLaunchKernelGGL(k_tabT, dim3(512), dim3(256), 0, stream, TabT);
    hipLaunchKernelGGL(k_gemm, dim3(16, 16, 3), dim3(256), 0, stream,
                       q, k, v, Twh, Twl, Part);
    hipLaunchKernelGGL(k_reduce, dim3(3072), dim3(256), 0, stream,
                       (const float4*)Part, (float4*)Qf, (float4*)Kf, (float4*)Vf);
    hipLaunchKernelGGL(k_qk, dim3(128, 2), dim3(256), 0, stream, Qf, Kf, QKt);
    hipLaunchKernelGGL(k_qkv, dim3(128, 2), dim3(256), 0, stream, Vf, QKt, QKV);
    hipLaunchKernelGGL(k_wt, dim3(64, 8), dim3(256), 0, stream, wr, wi, Wt);
    hipLaunchKernelGGL(k_qkvw, dim3(64, 8), dim3(256), 0, stream, QKV, Wt, QKVWs);
    hipLaunchKernelGGL(k_idft, dim3(32, 128), dim3(256), 0, stream, QKVWs, TabT, out);
}

// Round 4
// 170.002 us; speedup vs baseline: 1.3785x; 1.3785x over previous
//
#include <hip/hip_runtime.h>
#include <math.h>

// FourierCrossAttention: B=16, L=S=2048, H=8, E=O=64, M=64 (first 64 rfft modes)
// Pipeline: tables -> MFMA split-bf16 DFT(q,k,v) [K-split x2 + reduce] -> QK+tanh
//           -> QKV -> Wt -> QKVW -> MFMA iDFT
// DFT uses 3-product hi/lo bf16 split; iDFT uses 2-product (table hi/lo, X single bf16).

#define NB 16
#define NL 2048
#define NH 8
#define NE 64
#define NM 64
#define NHE 512  // H*E

typedef unsigned short ushort_t;
typedef __attribute__((ext_vector_type(8))) short short8;
typedef __attribute__((ext_vector_type(4))) float f32x4;

// DFT table layout: [64 ksteps][128 m'][32 shorts]
#define TW_ELEMS (64 * 128 * 32)

__device__ inline void gld_lds16(const void* g, void* l) {
    __builtin_amdgcn_global_load_lds((const __attribute__((address_space(1))) unsigned int*)g,
                                     (__attribute__((address_space(3))) unsigned int*)l, 16, 0, 0);
}

// ---------------- K0a: bf16 hi/lo twiddle tables for DFT ----------------
__global__ __launch_bounds__(256) void k_tables_gemm(ushort_t* __restrict__ Twh,
                                                     ushort_t* __restrict__ Twl) {
    int i = blockIdx.x * 256 + threadIdx.x;  // over 64*128*32 = 262144
    int s = i & 31;
    int mp = (i >> 5) & 127;
    int ks = i >> 12;
    int t = ks * 32 + s;
    int m = mp >> 1;
    float ang = (float)((6.283185307179586476925287 / (double)NL) * (double)((m * t) & (NL - 1)));
    float sv = sinf(ang);
    float cv = cosf(ang);
    float cf = (mp & 1) ? -sv : cv;
    unsigned cb = __float_as_uint(cf);
    unsigned hb = cb & 0xffff0000u;
    ushort_t h = (ushort_t)(cb >> 16);
    float lo = cf - __uint_as_float(hb);
    unsigned lb = __float_as_uint(lo);
    unsigned r = lb + 0x7fffu + ((lb >> 16) & 1u);
    ushort_t l = (ushort_t)(r >> 16);
    Twh[i] = h;
    Twl[i] = l;
}

// ---------------- K0b: iDFT twiddle hi/lo in MFMA fragment order ----------------
// Layout: [8 tt][4 ks][16 frag][64 lane][8 j]; t = tt*256 + f*16 + (l&15),
// k = ks*32 + (l>>4)*8 + j; value = (k odd) ? -sin(2pi t x / L) : cos, x = k>>1.
__global__ __launch_bounds__(256) void k_tables_idft(ushort_t* __restrict__ Ih,
                                                     ushort_t* __restrict__ Il) {
    int i = blockIdx.x * 256 + threadIdx.x;  // over 262144
    int j = i & 7;
    int l = (i >> 3) & 63;
    int f = (i >> 9) & 15;
    int ks = (i >> 13) & 3;
    int tt = i >> 15;
    int t = tt * 256 + f * 16 + (l & 15);
    int kk = ks * 32 + (l >> 4) * 8 + j;
    int x = kk >> 1;
    float ang = (float)((6.283185307179586476925287 / (double)NL) * (double)((t * x) & (NL - 1)));
    float val = (kk & 1) ? -sinf(ang) : cosf(ang);
    unsigned cb = __float_as_uint(val);
    ushort_t h = (ushort_t)(cb >> 16);
    float lo = val - __uint_as_float(cb & 0xffff0000u);
    unsigned lb = __float_as_uint(lo);
    unsigned r = lb + 0x7fffu + ((lb >> 16) & 1u);
    Ih[i] = h;
    Il[i] = (ushort_t)(r >> 16);
}

// ---------------- K1: MFMA DFT, K-split x2 ----------------
__global__ __launch_bounds__(256, 3) void k_gemm(
    const float* __restrict__ q, const float* __restrict__ k, const float* __restrict__ v,
    const ushort_t* __restrict__ Twh, const ushort_t* __restrict__ Twl,
    float* __restrict__ Part) {
    const int bx = blockIdx.x & 7;   // he-group 0..7
    const int kq = blockIdx.x >> 3;  // K-half 0..1
    const int b  = blockIdx.y;       // 0..15
    const int z  = blockIdx.z;       // 0..2
    const float* __restrict__ in = (z == 0) ? q : ((z == 1) ? k : v);

    const int tid  = threadIdx.x;
    const int wid  = tid >> 6;
    const int lane = tid & 63;
    const int lr   = lane & 15;
    const int lg   = lane >> 4;
    const int wy   = wid >> 1;
    const int wx   = wid & 1;
    const int he0  = bx * 64;

    __shared__ float    As[32 * 67];
    __shared__ ushort_t Bh[2][128 * 32];
    __shared__ ushort_t Bl[2][128 * 32];

    const int he4a = tid & 15;
    const int tt0  = tid >> 4;
    const size_t in_row_base = ((size_t)b * NL + kq * 1024) * NHE + he0 + he4a * 4;

    f32x4 acc[2][4];
#pragma unroll
    for (int f = 0; f < 2; ++f)
#pragma unroll
        for (int j = 0; j < 4; ++j) acc[f][j] = (f32x4){0.f, 0.f, 0.f, 0.f};

    {
        const int gks = kq * 32;
        const ushort_t* gh = Twh + (size_t)gks * 4096;
        const ushort_t* gl = Twl + (size_t)gks * 4096;
        gld_lds16(gh + (size_t)tid * 8, &Bh[0][tid * 8]);
        gld_lds16(gh + (size_t)(tid + 256) * 8, &Bh[0][(tid + 256) * 8]);
        gld_lds16(gl + (size_t)tid * 8, &Bl[0][tid * 8]);
        gld_lds16(gl + (size_t)(tid + 256) * 8, &Bl[0][(tid + 256) * 8]);
        float4 av0 = *(const float4*)(in + in_row_base + (size_t)tt0 * NHE);
        float4 av1 = *(const float4*)(in + in_row_base + (size_t)(tt0 + 16) * NHE);
        float* d0 = &As[tt0 * 67 + he4a * 4];
        d0[0] = av0.x; d0[1] = av0.y; d0[2] = av0.z; d0[3] = av0.w;
        float* d1 = &As[(tt0 + 16) * 67 + he4a * 4];
        d1[0] = av1.x; d1[1] = av1.y; d1[2] = av1.z; d1[3] = av1.w;
    }

    int cur = 0;
    for (int ks = 0; ks < 32; ++ks) {
        __syncthreads();
        const bool more = (ks + 1) < 32;
        float4 av0, av1;
        if (more) {
            const int gks = kq * 32 + ks + 1;
            const ushort_t* gh = Twh + (size_t)gks * 4096;
            const ushort_t* gl = Twl + (size_t)gks * 4096;
            ushort_t* lbh = &Bh[cur ^ 1][0];
            ushort_t* lbl = &Bl[cur ^ 1][0];
            gld_lds16(gh + (size_t)tid * 8, lbh + tid * 8);
            gld_lds16(gh + (size_t)(tid + 256) * 8, lbh + (tid + 256) * 8);
            gld_lds16(gl + (size_t)tid * 8, lbl + tid * 8);
            gld_lds16(gl + (size_t)(tid + 256) * 8, lbl + (tid + 256) * 8);
            const size_t tb = (size_t)(ks + 1) * 32;
            av0 = *(const float4*)(in + in_row_base + (tb + tt0) * NHE);
            av1 = *(const float4*)(in + in_row_base + (tb + tt0 + 16) * NHE);
        }

        const ushort_t* bhc = &Bh[cur][0];
        const ushort_t* blc = &Bl[cur][0];

        short8 ah[2], al[2];
#pragma unroll
        for (int f = 0; f < 2; ++f) {
            const int he = wy * 32 + f * 16 + lr;
            float xa[8];
#pragma unroll
            for (int j = 0; j < 8; ++j) xa[j] = As[(8 * lg + j) * 67 + he];
            union { unsigned u[4]; short8 s; } uh, ul;
#pragma unroll
            for (int p = 0; p < 4; ++p) {
                unsigned b0 = __float_as_uint(xa[2 * p]);
                unsigned b1 = __float_as_uint(xa[2 * p + 1]);
                uh.u[p] = (b0 >> 16) | (b1 & 0xffff0000u);
                float l0 = xa[2 * p]     - __uint_as_float(b0 & 0xffff0000u);
                float l1 = xa[2 * p + 1] - __uint_as_float(b1 & 0xffff0000u);
                unsigned lw;
                asm("v_cvt_pk_bf16_f32 %0, %1, %2" : "=v"(lw) : "v"(l0), "v"(l1));
                ul.u[p] = lw;
            }
            ah[f] = uh.s;
            al[f] = ul.s;
        }

        short8 bh8[4], bl8[4];
#pragma unroll
        for (int j = 0; j < 4; ++j) {
            const int mp = wx * 64 + j * 16 + lr;
            bh8[j] = *(const short8*)&bhc[mp * 32 + 8 * lg];
            bl8[j] = *(const short8*)&blc[mp * 32 + 8 * lg];
        }

#pragma unroll
        for (int f = 0; f < 2; ++f) {
#pragma unroll
            for (int j = 0; j < 4; ++j) {
                acc[f][j] = __builtin_amdgcn_mfma_f32_16x16x32_bf16(ah[f], bh8[j], acc[f][j], 0, 0, 0);
                acc[f][j] = __builtin_amdgcn_mfma_f32_16x16x32_bf16(ah[f], bl8[j], acc[f][j], 0, 0, 0);
                acc[f][j] = __builtin_amdgcn_mfma_f32_16x16x32_bf16(al[f], bh8[j], acc[f][j], 0, 0, 0);
            }
        }

        __syncthreads();
        if (more) {
            float* d0 = &As[tt0 * 67 + he4a * 4];
            d0[0] = av0.x; d0[1] = av0.y; d0[2] = av0.z; d0[3] = av0.w;
            float* d1 = &As[(tt0 + 16) * 67 + he4a * 4];
            d1[0] = av1.x; d1[1] = av1.y; d1[2] = av1.z; d1[3] = av1.w;
        }
        cur ^= 1;
    }

    float* pout = Part + (size_t)(z * 2 + kq) * 1048576;
#pragma unroll
    for (int f = 0; f < 2; ++f) {
#pragma unroll
        for (int j = 0; j < 4; ++j) {
            const int col = wx * 64 + j * 16 + lr;
#pragma unroll
            for (int r = 0; r < 4; ++r) {
                const int he = he0 + wy * 32 + f * 16 + 4 * lg + r;
                pout[((size_t)b * NHE + he) * 128 + col] = acc[f][j][r];
            }
        }
    }
}

// ---------------- K1b: reduce 2 K-half partials -> Qf/Kf/Vf ----------------
__global__ __launch_bounds__(256) void k_reduce(
    const float4* __restrict__ Part, float4* __restrict__ Qf,
    float4* __restrict__ Kf, float4* __restrict__ Vf) {
    int i = blockIdx.x * 256 + threadIdx.x;  // over 3*262144
    int z = i >> 18;
    int r = i & 262143;
    float4 a = Part[(size_t)(z * 2 + 0) * 262144 + r];
    float4 b = Part[(size_t)(z * 2 + 1) * 262144 + r];
    float4 s = make_float4(a.x + b.x, a.y + b.y, a.z + b.z, a.w + b.w);
    float4* o = (z == 0) ? Qf : ((z == 1) ? Kf : Vf);
    o[r] = s;
}

// ---------------- K2: QK = sum_e Qf[e,x]*Kf[e,y]; tanh re/im ----------------
__global__ __launch_bounds__(256) void k_qk(
    const float2* __restrict__ Qf, const float2* __restrict__ Kf,
    float2* __restrict__ QKt) {
    const int bh = blockIdx.x;  // 0..127
    const int xh = blockIdx.y;  // 0..1
    const int tid = threadIdx.x;
    __shared__ float2 Qs[64 * 34];
    __shared__ float2 Ks[64 * 66];

    const float2* Qbase = Qf + (size_t)bh * (NE * NM);
    const float2* Kbase = Kf + (size_t)bh * (NE * NM);
#pragma unroll
    for (int j = 0; j < 4; ++j) {
        int n = tid + j * 256;  // 1024 f4
        int e = n >> 4, c = n & 15;
        float4 val = ((const float4*)(Qbase + e * NM + xh * 32))[c];
        *((float4*)&Qs[e * 34 + c * 2]) = val;
    }
#pragma unroll
    for (int j = 0; j < 8; ++j) {
        int n = tid + j * 256;  // 2048 f4
        int e = n >> 5, c = n & 31;
        float4 val = ((const float4*)(Kbase + e * NM))[c];
        *((float4*)&Ks[e * 66 + c * 2]) = val;
    }
    __syncthreads();

    const int yq = tid & 31, xq = tid >> 5;
    float accr[4][2], acci[4][2];
#pragma unroll
    for (int i = 0; i < 4; ++i)
#pragma unroll
        for (int j = 0; j < 2; ++j) { accr[i][j] = 0.f; acci[i][j] = 0.f; }

    for (int e = 0; e < 64; ++e) {
        float4 qa = *((float4*)&Qs[e * 34 + xq * 4]);
        float4 qb = *((float4*)&Qs[e * 34 + xq * 4 + 2]);
        float4 kk = *((float4*)&Ks[e * 66 + yq * 2]);
        float qr[4] = {qa.x, qa.z, qb.x, qb.z};
        float qi[4] = {qa.y, qa.w, qb.y, qb.w};
        float kr[2] = {kk.x, kk.z};
        float ki[2] = {kk.y, kk.w};
#pragma unroll
        for (int i = 0; i < 4; ++i) {
#pragma unroll
            for (int j = 0; j < 2; ++j) {
                accr[i][j] += qr[i] * kr[j] - qi[i] * ki[j];
                acci[i][j] += qr[i] * ki[j] + qi[i] * kr[j];
            }
        }
    }
    const int x0 = xh * 32 + xq * 4;
#pragma unroll
    for (int i = 0; i < 4; ++i) {
        float4 sv = make_float4(tanhf(accr[i][0]), tanhf(acci[i][0]),
                                tanhf(accr[i][1]), tanhf(acci[i][1]));
        *((float4*)&QKt[(size_t)bh * 4096 + (x0 + i) * 64 + yq * 2]) = sv;
    }
}

// ---------------- K3: QKV[e,x] = sum_y Vf[e,y]*QKt[x,y] ----------------
__global__ __launch_bounds__(256) void k_qkv(
    const float2* __restrict__ Vf, const float2* __restrict__ QKt,
    float2* __restrict__ QKV) {
    const int bh = blockIdx.x;
    const int eh = blockIdx.y;
    const int tid = threadIdx.x;
    __shared__ float2 Vs[32 * 66];
    __shared__ float2 Ps[64 * 66];

    const float2* Vbase = Vf + (size_t)bh * (NE * NM) + eh * 32 * NM;
    const float2* Pbase = QKt + (size_t)bh * 4096;
#pragma unroll
    for (int j = 0; j < 4; ++j) {
        int n = tid + j * 256;
        int r = n >> 5, c = n & 31;
        float4 val = ((const float4*)(Vbase + r * NM))[c];
        *((float4*)&Vs[r * 66 + c * 2]) = val;
    }
#pragma unroll
    for (int j = 0; j < 8; ++j) {
        int n = tid + j * 256;
        int r = n >> 5, c = n & 31;
        float4 val = ((const float4*)(Pbase + r * NM))[c];
        *((float4*)&Ps[r * 66 + c * 2]) = val;
    }
    __syncthreads();

    const int xq = tid & 15, eq2 = tid >> 4;
    const int x0 = xq * 4, e0 = eq2 * 2;
    float accr[2][4], acci[2][4];
#pragma unroll
    for (int i = 0; i < 2; ++i)
#pragma unroll
        for (int j = 0; j < 4; ++j) { accr[i][j] = 0.f; acci[i][j] = 0.f; }

    for (int yy = 0; yy < 64; ++yy) {
        float2 v0 = Vs[(e0 + 0) * 66 + yy];
        float2 v1 = Vs[(e0 + 1) * 66 + yy];
        float2 p0 = Ps[(x0 + 0) * 66 + yy];
        float2 p1 = Ps[(x0 + 1) * 66 + yy];
        float2 p2 = Ps[(x0 + 2) * 66 + yy];
        float2 p3 = Ps[(x0 + 3) * 66 + yy];
        float pr[4] = {p0.x, p1.x, p2.x, p3.x};
        float pi[4] = {p0.y, p1.y, p2.y, p3.y};
#pragma unroll
        for (int j = 0; j < 4; ++j) {
            accr[0][j] += v0.x * pr[j] - v0.y * pi[j];
            acci[0][j] += v0.x * pi[j] + v0.y * pr[j];
            accr[1][j] += v1.x * pr[j] - v1.y * pi[j];
            acci[1][j] += v1.x * pi[j] + v1.y * pr[j];
        }
    }
#pragma unroll
    for (int e = 0; e < 2; ++e) {
        float2* obase = QKV + (size_t)bh * 4096 + (eh * 32 + e0 + e) * 64 + x0;
        float4 s0 = make_float4(accr[e][0], acci[e][0], accr[e][1], acci[e][1]);
        float4 s1 = make_float4(accr[e][2], acci[e][2], accr[e][3], acci[e][3]);
        ((float4*)obase)[0] = s0;
        ((float4*)obase)[1] = s1;
    }
}

// ---------------- K4a: transpose W -> Wt[h][x][e][o] ----------------
__global__ __launch_bounds__(256) void k_wt(
    const float* __restrict__ wr, const float* __restrict__ wi,
    float2* __restrict__ Wt) {
    const int e = blockIdx.x, h = blockIdx.y;
    const int tid = threadIdx.x;
    __shared__ float lr[64 * 68];
    __shared__ float li[64 * 68];
    const float* rbase = wr + (size_t)(h * NE + e) * NE * NM;
    const float* ibase = wi + (size_t)(h * NE + e) * NE * NM;
#pragma unroll
    for (int j = 0; j < 4; ++j) {
        int n = tid + j * 256;
        int o = n >> 4, x4 = n & 15;
        float4 r4 = ((const float4*)(rbase + o * NM))[x4];
        float4 i4 = ((const float4*)(ibase + o * NM))[x4];
        *((float4*)&lr[o * 68 + x4 * 4]) = r4;
        *((float4*)&li[o * 68 + x4 * 4]) = i4;
    }
    __syncthreads();
#pragma unroll
    for (int j = 0; j < 16; ++j) {
        int n = tid + j * 256;
        int x = n >> 6, o = n & 63;
        Wt[((size_t)(h * NM + x) * NE + e) * NE + o] =
            make_float2(lr[o * 68 + x], li[o * 68 + x]);
    }
}

// ---------------- K4: QKVW[o,x] = sum_e QKV[e,x]*W[e,o,x], scaled for irfft ----------------
__global__ __launch_bounds__(256) void k_qkvw(
    const float2* __restrict__ QKV, const float2* __restrict__ Wt,
    float2* __restrict__ QKVWs) {
    const int x = blockIdx.x, h = blockIdx.y;
    const int tid = threadIdx.x;
    const int o = tid & 63, bq = tid >> 6;
    float accr[4], acci[4];
#pragma unroll
    for (int j = 0; j < 4; ++j) { accr[j] = 0.f; acci[j] = 0.f; }

    const float2* wbase = Wt + (size_t)(h * NM + x) * NE * NE + o;
    for (int e = 0; e < 64; ++e) {
        float2 w = wbase[(size_t)e * NE];
#pragma unroll
        for (int j = 0; j < 4; ++j) {
            int b = bq * 4 + j;
            float2 a = QKV[((size_t)(b * NH + h) * NE + e) * NM + x];
            accr[j] += a.x * w.x - a.y * w.y;
            acci[j] += a.x * w.y + a.y * w.x;
        }
    }
    const float sc = (x == 0) ? (1.f / NL) : (2.f / NL);
#pragma unroll
    for (int j = 0; j < 4; ++j) {
        int b = bq * 4 + j;
        QKVWs[((size_t)(b * NH + h) * NM + x) * NE + o] =
            make_float2(accr[j] * sc, acci[j] * sc);
    }
}

// ---------------- K5: MFMA iDFT + transpose to [B,L,H,O] ----------------
// Per (bh, tt): C[256t][64o] = A[256t][128k] * B[128k][64o],
// A = frag-ordered hi/lo twiddle (staged linearly), B = X as bf16 (in-reg cvt).
__global__ __launch_bounds__(256, 3) void k_idft(
    const float2* __restrict__ QKVWs,
    const ushort_t* __restrict__ Ih, const ushort_t* __restrict__ Il,
    float* __restrict__ yout) {
    const int tt = blockIdx.x;   // 0..7
    const int bh = blockIdx.y;   // 0..127
    const int b = bh >> 3, h = bh & 7;
    const int tid = threadIdx.x;
    const int wid = tid >> 6;
    const int lane = tid & 63;
    const int lr = lane & 15;
    const int lg = lane >> 4;

    __shared__ ushort_t Ta[8192];   // hi tile: [16 frag][64 lane][8]
    __shared__ ushort_t Tb[8192];   // lo tile
    __shared__ unsigned Xs[4096];   // X bf16 pairs, frag order [4ks][4jn][64lane][4]

    // ---- X prep: QKVWs[bh] = [64x][64o] complex -> bf16 frag layout ----
    const float2* xb = QKVWs + (size_t)bh * 4096;
#pragma unroll
    for (int r = 0; r < 16; ++r) {
        int i = tid + r * 256;
        int x = i >> 6, o = i & 63;
        float2 val = xb[i];
        int ks = x >> 4;
        int lane2 = (((x & 15) >> 2) << 4) | (o & 15);
        int jn = o >> 4;
        unsigned pk;
        asm("v_cvt_pk_bf16_f32 %0, %1, %2" : "=v"(pk) : "v"(val.x), "v"(val.y));
        Xs[((ks * 4 + jn) * 64 + lane2) * 4 + (x & 3)] = pk;
    }
    // ---- stage kstep 0 ----
    {
        const ushort_t* gh = Ih + (size_t)(tt * 4) * 8192;
        const ushort_t* gl = Il + (size_t)(tt * 4) * 8192;
#pragma unroll
        for (int p = 0; p < 4; ++p) {
            gld_lds16(gh + (size_t)(tid + p * 256) * 8, &Ta[(tid + p * 256) * 8]);
            gld_lds16(gl + (size_t)(tid + p * 256) * 8, &Tb[(tid + p * 256) * 8]);
        }
    }
    __syncthreads();

    f32x4 acc[4][4];
#pragma unroll
    for (int m = 0; m < 4; ++m)
#pragma unroll
        for (int n = 0; n < 4; ++n) acc[m][n] = (f32x4){0.f, 0.f, 0.f, 0.f};

    const ushort_t* XsS = (const ushort_t*)Xs;
    for (int ks = 0; ks < 4; ++ks) {
        short8 ah[4], al[4], bx[4];
#pragma unroll
        for (int m = 0; m < 4; ++m) {
            const int fr = wid * 4 + m;
            ah[m] = *(const short8*)&Ta[(fr * 64 + lane) * 8];
            al[m] = *(const short8*)&Tb[(fr * 64 + lane) * 8];
        }
#pragma unroll
        for (int n = 0; n < 4; ++n) {
            bx[n] = *(const short8*)&XsS[((ks * 4 + n) * 64 + lane) * 8];
        }
#pragma unroll
        for (int m = 0; m < 4; ++m) {
#pragma unroll
            for (int n = 0; n < 4; ++n) {
                acc[m][n] = __builtin_amdgcn_mfma_f32_16x16x32_bf16(ah[m], bx[n], acc[m][n], 0, 0, 0);
                acc[m][n] = __builtin_amdgcn_mfma_f32_16x16x32_bf16(al[m], bx[n], acc[m][n], 0, 0, 0);
            }
        }
        if (ks < 3) {
            __syncthreads();  // all ds_reads of Ta/Tb landed in regs
            const ushort_t* gh = Ih + (size_t)(tt * 4 + ks + 1) * 8192;
            const ushort_t* gl = Il + (size_t)(tt * 4 + ks + 1) * 8192;
#pragma unroll
            for (int p = 0; p < 4; ++p) {
                gld_lds16(gh + (size_t)(tid + p * 256) * 8, &Ta[(tid + p * 256) * 8]);
                gld_lds16(gl + (size_t)(tid + p * 256) * 8, &Tb[(tid + p * 256) * 8]);
            }
            __syncthreads();  // staging drained (vmcnt before barrier)
        }
    }

    // ---- epilogue ----
    const int t0 = tt * 256 + wid * 64;
#pragma unroll
    for (int m = 0; m < 4; ++m) {
#pragma unroll
        for (int n = 0; n < 4; ++n) {
            const int o = n * 16 + lr;
#pragma unroll
            for (int r = 0; r < 4; ++r) {
                const int t = t0 + m * 16 + lg * 4 + r;
                yout[(((size_t)b * NL + t) * NH + h) * NE + o] = acc[m][n][r];
            }
        }
    }
}

extern "C" void kernel_launch(void* const* d_in, const int* in_sizes, int n_in,
                              void* d_out, int out_size, void* d_ws, size_t ws_size,
                              hipStream_t stream) {
    const float* q  = (const float*)d_in[0];
    const float* k  = (const float*)d_in[1];
    const float* v  = (const float*)d_in[2];
    const float* wr = (const float*)d_in[3];
    const float* wi = (const float*)d_in[4];
    float* out = (float*)d_out;

    // workspace layout (bytes); Part overlays the post-reduce tail (QKt/QKV/Wt)
    char* w = (char*)d_ws;
    ushort_t* Twh  = (ushort_t*)w;                      //   524,288 B
    ushort_t* Twl  = (ushort_t*)(w + 524288);           //   524,288 B
    ushort_t* ITwh = (ushort_t*)(w + 1048576);          //   524,288 B
    ushort_t* ITwl = (ushort_t*)(w + 1572864);          //   524,288 B
    float2*   Qf   = (float2*)(w + 2097152);            // 4,194,304 B each below
    float2*   Kf   = (float2*)(w + 6291456);
    float2*   Vf   = (float2*)(w + 10485760);
    float*    Part = (float*)(w + 14680064);            // 25,165,824 B (6 x 1M floats)
    float2*   QKt  = (float2*)(w + 14680064);           // overlays Part (post-reduce)
    float2*   QKV  = (float2*)(w + 18874368);
    float2*   Wt   = (float2*)(w + 23068672);           // 16,777,216 B
    float2*   QKVWs= (float2*)(w + 39845888);           // 4,194,304 B
    // total = 44,040,192 B

    hipLaunchKernelGGL(k_tables_gemm, dim3(1024), dim3(256), 0, stream, Twh, Twl);
    hipLaunchKernelGGL(k_tables_idft, dim3(1024), dim3(256), 0, stream, ITwh, ITwl);
    hipLaunchKernelGGL(k_gemm, dim3(16, 16, 3), dim3(256), 0, stream,
                       q, k, v, Twh, Twl, Part);
    hipLaunchKernelGGL(k_reduce, dim3(3072), dim3(256), 0, stream,
                       (const float4*)Part, (float4*)Qf, (float4*)Kf, (float4*)Vf);
    hipLaunchKernelGGL(k_qk, dim3(128, 2), dim3(256), 0, stream, Qf, Kf, QKt);
    hipLaunchKernelGGL(k_qkv, dim3(128, 2), dim3(256), 0, stream, Vf, QKt, QKV);
    hipLaunchKernelGGL(k_wt, dim3(64, 8), dim3(256), 0, stream, wr, wi, Wt);
    hipLaunchKernelGGL(k_qkvw, dim3(64, 8), dim3(256), 0, stream, QKV, Wt, QKVWs);
    hipLaunchKernelGGL(k_idft, dim3(8, 128), dim3(256), 0, stream, QKVWs, ITwh, ITwl, out);
}

// Round 6
// 155.260 us; speedup vs baseline: 1.5094x; 1.0949x over previous
//
#include <hip/hip_runtime.h>
#include <hip/hip_fp16.h>
#include <math.h>

// FourierCrossAttention: B=16, L=S=2048, H=8, E=O=64, M=64 (first 64 rfft modes)
// Pipeline: tables -> MFMA bf16 3-product DFT(q,k,v) [K-split x2 + reduce] -> QK+tanh
//           -> QKV -> Wt -> QKVW(x1024) -> MFMA fp16 1-product iDFT (/1024)
// DFT: bf16 hi/lo split on BOTH operands, drop lo*lo (R4-verified numerics);
//      tables in MFMA fragment order (conflict-free ds_read_b128), A via gld_lds+XOR swizzle.

#define NB 16
#define NL 2048
#define NH 8
#define NE 64
#define NM 64
#define NHE 512  // H*E

typedef unsigned short ushort_t;
typedef __attribute__((ext_vector_type(8))) short short8;
typedef __attribute__((ext_vector_type(8))) _Float16 half8;
typedef __attribute__((ext_vector_type(4))) float f32x4;

__device__ inline void gld_lds16(const void* g, void* l) {
    __builtin_amdgcn_global_load_lds((const __attribute__((address_space(1))) unsigned int*)g,
                                     (__attribute__((address_space(3))) unsigned int*)l, 16, 0, 0);
}

// ---------------- K0a: bf16 hi/lo DFT twiddle tables in MFMA fragment order ----------------
// flat i = ks*4096 + g*512 + l*8 + kj ; mp = g*16 + (l&15), kk = (l>>4)*8 + kj,
// t = ks*32 + kk, m = mp>>1 ; val = (mp odd) ? -sin(2pi m t/L) : cos(2pi m t/L)
// hi = truncate-top16(val), lo = RNE-bf16(val - hi)   (R4-verified split)
__global__ __launch_bounds__(256) void k_tables_gemm(ushort_t* __restrict__ Twh,
                                                     ushort_t* __restrict__ Twl) {
    int i = blockIdx.x * 256 + threadIdx.x;  // over 64*4096 = 262144
    int kj = i & 7;
    int l  = (i >> 3) & 63;
    int g  = (i >> 9) & 7;
    int ks = i >> 12;
    int mp = g * 16 + (l & 15);
    int kk = (l >> 4) * 8 + kj;
    int t = ks * 32 + kk;
    int m = mp >> 1;
    float ang = (float)((6.283185307179586476925287 / (double)NL) * (double)((m * t) & (NL - 1)));
    float val = (mp & 1) ? -sinf(ang) : cosf(ang);
    unsigned cb = __float_as_uint(val);
    ushort_t h = (ushort_t)(cb >> 16);
    float lo = val - __uint_as_float(cb & 0xffff0000u);
    unsigned lb = __float_as_uint(lo);
    unsigned r = lb + 0x7fffu + ((lb >> 16) & 1u);
    Twh[i] = h;
    Twl[i] = (ushort_t)(r >> 16);
}

// ---------------- K0b: fp16 iDFT twiddle in MFMA fragment order ----------------
// Layout: [8 tt][4 ks][16 frag][64 lane][8 j]; t = tt*256 + f*16 + (l&15),
// k = ks*32 + (l>>4)*8 + j; value = (k odd) ? -sin(2pi t x / L) : cos, x = k>>1.
__global__ __launch_bounds__(256) void k_tables_idft(ushort_t* __restrict__ Ih) {
    int i = blockIdx.x * 256 + threadIdx.x;  // over 262144
    int j = i & 7;
    int l = (i >> 3) & 63;
    int f = (i >> 9) & 15;
    int ks = (i >> 13) & 3;
    int tt = i >> 15;
    int t = tt * 256 + f * 16 + (l & 15);
    int kk = ks * 32 + (l >> 4) * 8 + j;
    int x = kk >> 1;
    float ang = (float)((6.283185307179586476925287 / (double)NL) * (double)((t * x) & (NL - 1)));
    float val = (kk & 1) ? -sinf(ang) : cosf(ang);
    Ih[i] = __half_as_ushort(__float2half(val));
}

// ---------------- K1: MFMA bf16 3-product DFT, K-split x2 ----------------
// Cpart[he, m'] = sum_t X[t, he] * Tw[t, m'] per (b, z, kq). Block 64he x 128m',
// BK=32, 32 ksteps, 4 waves (2wy x 2wx), wave tile 32x64 (2x4 acc of 16x16).
// A: raw fp32 [32t][64he] via gld_lds, XOR-swizzled (he bit4 ^= t bit3, both sides);
// B: fragment-order bf16 hi/lo tables via gld_lds (conflict-free). One barrier/kstep.
__global__ __launch_bounds__(256, 3) void k_gemm(
    const float* __restrict__ q, const float* __restrict__ k, const float* __restrict__ v,
    const ushort_t* __restrict__ Twh, const ushort_t* __restrict__ Twl,
    float* __restrict__ Part) {
    const int bx = blockIdx.x & 7;   // he-group 0..7 (64 each)
    const int kq = blockIdx.x >> 3;  // K-half 0..1
    const int b  = blockIdx.y;       // 0..15
    const int z  = blockIdx.z;       // 0..2
    const float* __restrict__ in = (z == 0) ? q : ((z == 1) ? k : v);

    const int tid  = threadIdx.x;
    const int wid  = tid >> 6;
    const int lane = tid & 63;
    const int lr   = lane & 15;
    const int lg   = lane >> 4;
    const int wy   = wid >> 1;  // he-half -> +32
    const int wx   = wid & 1;   // m-half  -> +64
    const int he0  = bx * 64;
    const int fx   = lg & 1;    // A-swizzle bit (t bit3) for this lane's k-group

    __shared__ float    As[2][32 * 64];   // raw fp32, he-swizzled, 8 KB each
    __shared__ ushort_t Bh[2][4096];      // frag-order bf16 hi, 8 KB each
    __shared__ ushort_t Bl[2][4096];      // frag-order bf16 lo, 8 KB each

    f32x4 acc[2][4];
#pragma unroll
    for (int f = 0; f < 2; ++f)
#pragma unroll
        for (int j = 0; j < 4; ++j) acc[f][j] = (f32x4){0.f, 0.f, 0.f, 0.f};

    const size_t in_blk = ((size_t)b * NL + (size_t)kq * 1024) * NHE + he0;

    // ---- stage kstep `ksn` into buffer `n` (pure gld_lds) ----
#define STAGE(n, ksn)                                                                 \
    {                                                                                 \
        const ushort_t* gh = Twh + (size_t)(kq * 32 + (ksn)) * 4096;                  \
        const ushort_t* gl = Twl + (size_t)(kq * 32 + (ksn)) * 4096;                  \
        gld_lds16(gh + (size_t)tid * 8, &Bh[n][tid * 8]);                             \
        gld_lds16(gh + (size_t)(tid + 256) * 8, &Bh[n][(tid + 256) * 8]);             \
        gld_lds16(gl + (size_t)tid * 8, &Bl[n][tid * 8]);                             \
        gld_lds16(gl + (size_t)(tid + 256) * 8, &Bl[n][(tid + 256) * 8]);             \
        const float* ga = in + in_blk + (size_t)(ksn) * 32 * NHE;                     \
        _Pragma("unroll")                                                             \
        for (int p = 0; p < 2; ++p) {                                                 \
            int u = tid + p * 256;                                                    \
            int tloc = u >> 4, hc = u & 15;                                           \
            int hcs = hc ^ (((tloc >> 3) & 1) << 2);                                  \
            gld_lds16(ga + (size_t)tloc * NHE + hcs * 4, &As[n][u * 4]);              \
        }                                                                             \
    }

    STAGE(0, 0);

    int cur = 0;
    for (int ks = 0; ks < 32; ++ks) {
        __syncthreads();  // drains all gld_lds issued for buf `cur`
        if (ks + 1 < 32) STAGE(cur ^ 1, ks + 1);

        // ---- compute on buffer cur ----
        const float* ac = &As[cur][0];
        const ushort_t* bhc = &Bh[cur][0];
        const ushort_t* blc = &Bl[cur][0];

        short8 bh8[4], bl8[4];
#pragma unroll
        for (int j = 0; j < 4; ++j) {
            bh8[j] = *(const short8*)&bhc[((wx * 4 + j) * 64 + lane) * 8];
            bl8[j] = *(const short8*)&blc[((wx * 4 + j) * 64 + lane) * 8];
        }

#pragma unroll
        for (int f = 0; f < 2; ++f) {
            const int col = wy * 32 + ((f ^ fx) << 4) + lr;  // he ^ swizzle
            float xa[8];
#pragma unroll
            for (int j = 0; j < 8; ++j) xa[j] = ac[(8 * lg + j) * 64 + col];
            union { unsigned u[4]; short8 s; } uh, ul;
#pragma unroll
            for (int p = 0; p < 4; ++p) {
                unsigned b0 = __float_as_uint(xa[2 * p]);
                unsigned b1 = __float_as_uint(xa[2 * p + 1]);
                uh.u[p] = (b0 >> 16) | (b1 & 0xffff0000u);
                float l0 = xa[2 * p]     - __uint_as_float(b0 & 0xffff0000u);
                float l1 = xa[2 * p + 1] - __uint_as_float(b1 & 0xffff0000u);
                unsigned lw;
                asm("v_cvt_pk_bf16_f32 %0, %1, %2" : "=v"(lw) : "v"(l0), "v"(l1));
                ul.u[p] = lw;
            }
#pragma unroll
            for (int j = 0; j < 4; ++j) {
                acc[f][j] = __builtin_amdgcn_mfma_f32_16x16x32_bf16(uh.s, bh8[j], acc[f][j], 0, 0, 0);
                acc[f][j] = __builtin_amdgcn_mfma_f32_16x16x32_bf16(ul.s, bh8[j], acc[f][j], 0, 0, 0);
                acc[f][j] = __builtin_amdgcn_mfma_f32_16x16x32_bf16(uh.s, bl8[j], acc[f][j], 0, 0, 0);
            }
        }
        cur ^= 1;
    }
#undef STAGE

    // ---- epilogue: Part[(z*2+kq)][(b*512+he)][m'] (R4-identical layout) ----
    float* pout = Part + (size_t)(z * 2 + kq) * 1048576;
#pragma unroll
    for (int f = 0; f < 2; ++f) {
#pragma unroll
        for (int j = 0; j < 4; ++j) {
            const int col = wx * 64 + j * 16 + lr;
#pragma unroll
            for (int r = 0; r < 4; ++r) {
                const int he = he0 + wy * 32 + f * 16 + 4 * lg + r;
                pout[((size_t)b * NHE + he) * 128 + col] = acc[f][j][r];
            }
        }
    }
}

// ---------------- K1b: reduce 2 K-half partials -> Qf/Kf/Vf ----------------
__global__ __launch_bounds__(256) void k_reduce(
    const float4* __restrict__ Part, float4* __restrict__ Qf,
    float4* __restrict__ Kf, float4* __restrict__ Vf) {
    int i = blockIdx.x * 256 + threadIdx.x;  // over 3*262144
    int z = i >> 18;
    int r = i & 262143;
    float4 a = Part[(size_t)(z * 2 + 0) * 262144 + r];
    float4 b = Part[(size_t)(z * 2 + 1) * 262144 + r];
    float4 s = make_float4(a.x + b.x, a.y + b.y, a.z + b.z, a.w + b.w);
    float4* o = (z == 0) ? Qf : ((z == 1) ? Kf : Vf);
    o[r] = s;
}

// ---------------- K2: QK = sum_e Qf[e,x]*Kf[e,y]; tanh re/im ----------------
__global__ __launch_bounds__(256) void k_qk(
    const float2* __restrict__ Qf, const float2* __restrict__ Kf,
    float2* __restrict__ QKt) {
    const int bh = blockIdx.x;  // 0..127
    const int xh = blockIdx.y;  // 0..1
    const int tid = threadIdx.x;
    __shared__ float2 Qs[64 * 34];
    __shared__ float2 Ks[64 * 66];

    const float2* Qbase = Qf + (size_t)bh * (NE * NM);
    const float2* Kbase = Kf + (size_t)bh * (NE * NM);
#pragma unroll
    for (int j = 0; j < 4; ++j) {
        int n = tid + j * 256;  // 1024 f4
        int e = n >> 4, c = n & 15;
        float4 val = ((const float4*)(Qbase + e * NM + xh * 32))[c];
        *((float4*)&Qs[e * 34 + c * 2]) = val;
    }
#pragma unroll
    for (int j = 0; j < 8; ++j) {
        int n = tid + j * 256;  // 2048 f4
        int e = n >> 5, c = n & 31;
        float4 val = ((const float4*)(Kbase + e * NM))[c];
        *((float4*)&Ks[e * 66 + c * 2]) = val;
    }
    __syncthreads();

    const int yq = tid & 31, xq = tid >> 5;
    float accr[4][2], acci[4][2];
#pragma unroll
    for (int i = 0; i < 4; ++i)
#pragma unroll
        for (int j = 0; j < 2; ++j) { accr[i][j] = 0.f; acci[i][j] = 0.f; }

    for (int e = 0; e < 64; ++e) {
        float4 qa = *((float4*)&Qs[e * 34 + xq * 4]);
        float4 qb = *((float4*)&Qs[e * 34 + xq * 4 + 2]);
        float4 kk = *((float4*)&Ks[e * 66 + yq * 2]);
        float qr[4] = {qa.x, qa.z, qb.x, qb.z};
        float qi[4] = {qa.y, qa.w, qb.y, qb.w};
        float kr[2] = {kk.x, kk.z};
        float ki[2] = {kk.y, kk.w};
#pragma unroll
        for (int i = 0; i < 4; ++i) {
#pragma unroll
            for (int j = 0; j < 2; ++j) {
                accr[i][j] += qr[i] * kr[j] - qi[i] * ki[j];
                acci[i][j] += qr[i] * ki[j] + qi[i] * kr[j];
            }
        }
    }
    const int x0 = xh * 32 + xq * 4;
#pragma unroll
    for (int i = 0; i < 4; ++i) {
        float4 sv = make_float4(tanhf(accr[i][0]), tanhf(acci[i][0]),
                                tanhf(accr[i][1]), tanhf(acci[i][1]));
        *((float4*)&QKt[(size_t)bh * 4096 + (x0 + i) * 64 + yq * 2]) = sv;
    }
}

// ---------------- K3: QKV[e,x] = sum_y Vf[e,y]*QKt[x,y] ----------------
__global__ __launch_bounds__(256) void k_qkv(
    const float2* __restrict__ Vf, const float2* __restrict__ QKt,
    float2* __restrict__ QKV) {
    const int bh = blockIdx.x;
    const int eh = blockIdx.y;
    const int tid = threadIdx.x;
    __shared__ float2 Vs[32 * 66];
    __shared__ float2 Ps[64 * 66];

    const float2* Vbase = Vf + (size_t)bh * (NE * NM) + eh * 32 * NM;
    const float2* Pbase = QKt + (size_t)bh * 4096;
#pragma unroll
    for (int j = 0; j < 4; ++j) {
        int n = tid + j * 256;
        int r = n >> 5, c = n & 31;
        float4 val = ((const float4*)(Vbase + r * NM))[c];
        *((float4*)&Vs[r * 66 + c * 2]) = val;
    }
#pragma unroll
    for (int j = 0; j < 8; ++j) {
        int n = tid + j * 256;
        int r = n >> 5, c = n & 31;
        float4 val = ((const float4*)(Pbase + r * NM))[c];
        *((float4*)&Ps[r * 66 + c * 2]) = val;
    }
    __syncthreads();

    const int xq = tid & 15, eq2 = tid >> 4;
    const int x0 = xq * 4, e0 = eq2 * 2;
    float accr[2][4], acci[2][4];
#pragma unroll
    for (int i = 0; i < 2; ++i)
#pragma unroll
        for (int j = 0; j < 4; ++j) { accr[i][j] = 0.f; acci[i][j] = 0.f; }

    for (int yy = 0; yy < 64; ++yy) {
        float2 v0 = Vs[(e0 + 0) * 66 + yy];
        float2 v1 = Vs[(e0 + 1) * 66 + yy];
        float2 p0 = Ps[(x0 + 0) * 66 + yy];
        float2 p1 = Ps[(x0 + 1) * 66 + yy];
        float2 p2 = Ps[(x0 + 2) * 66 + yy];
        float2 p3 = Ps[(x0 + 3) * 66 + yy];
        float pr[4] = {p0.x, p1.x, p2.x, p3.x};
        float pi[4] = {p0.y, p1.y, p2.y, p3.y};
#pragma unroll
        for (int j = 0; j < 4; ++j) {
            accr[0][j] += v0.x * pr[j] - v0.y * pi[j];
            acci[0][j] += v0.x * pi[j] + v0.y * pr[j];
            accr[1][j] += v1.x * pr[j] - v1.y * pi[j];
            acci[1][j] += v1.x * pi[j] + v1.y * pr[j];
        }
    }
#pragma unroll
    for (int e = 0; e < 2; ++e) {
        float2* obase = QKV + (size_t)bh * 4096 + (eh * 32 + e0 + e) * 64 + x0;
        float4 s0 = make_float4(accr[e][0], acci[e][0], accr[e][1], acci[e][1]);
        float4 s1 = make_float4(accr[e][2], acci[e][2], accr[e][3], acci[e][3]);
        ((float4*)obase)[0] = s0;
        ((float4*)obase)[1] = s1;
    }
}

// ---------------- K4a: transpose W -> Wt[h][x][e][o] ----------------
__global__ __launch_bounds__(256) void k_wt(
    const float* __restrict__ wr, const float* __restrict__ wi,
    float2* __restrict__ Wt) {
    const int e = blockIdx.x, h = blockIdx.y;
    const int tid = threadIdx.x;
    __shared__ float lr[64 * 68];
    __shared__ float li[64 * 68];
    const float* rbase = wr + (size_t)(h * NE + e) * NE * NM;
    const float* ibase = wi + (size_t)(h * NE + e) * NE * NM;
#pragma unroll
    for (int j = 0; j < 4; ++j) {
        int n = tid + j * 256;
        int o = n >> 4, x4 = n & 15;
        float4 r4 = ((const float4*)(rbase + o * NM))[x4];
        float4 i4 = ((const float4*)(ibase + o * NM))[x4];
        *((float4*)&lr[o * 68 + x4 * 4]) = r4;
        *((float4*)&li[o * 68 + x4 * 4]) = i4;
    }
    __syncthreads();
#pragma unroll
    for (int j = 0; j < 16; ++j) {
        int n = tid + j * 256;
        int x = n >> 6, o = n & 63;
        Wt[((size_t)(h * NM + x) * NE + e) * NE + o] =
            make_float2(lr[o * 68 + x], li[o * 68 + x]);
    }
}

// ---------------- K4: QKVW[o,x] = sum_e QKV[e,x]*W[e,o,x], irfft scale x1024 ----------------
__global__ __launch_bounds__(256) void k_qkvw(
    const float2* __restrict__ QKV, const float2* __restrict__ Wt,
    float2* __restrict__ QKVWs) {
    const int x = blockIdx.x, h = blockIdx.y;
    const int tid = threadIdx.x;
    const int o = tid & 63, bq = tid >> 6;
    float accr[4], acci[4];
#pragma unroll
    for (int j = 0; j < 4; ++j) { accr[j] = 0.f; acci[j] = 0.f; }

    const float2* wbase = Wt + (size_t)(h * NM + x) * NE * NE + o;
    for (int e = 0; e < 64; ++e) {
        float2 w = wbase[(size_t)e * NE];
#pragma unroll
        for (int j = 0; j < 4; ++j) {
            int b = bq * 4 + j;
            float2 a = QKV[((size_t)(b * NH + h) * NE + e) * NM + x];
            accr[j] += a.x * w.x - a.y * w.y;
            acci[j] += a.x * w.y + a.y * w.x;
        }
    }
    // (1/NL or 2/NL) * 1024 (exact powers of 2); undone by /1024 in k_idft epilogue
    const float sc = (x == 0) ? 0.5f : 1.0f;
#pragma unroll
    for (int j = 0; j < 4; ++j) {
        int b = bq * 4 + j;
        QKVWs[((size_t)(b * NH + h) * NM + x) * NE + o] =
            make_float2(accr[j] * sc, acci[j] * sc);
    }
}

// ---------------- K5: MFMA fp16 1-product iDFT + transpose to [B,L,H,O] ----------------
__global__ __launch_bounds__(256, 3) void k_idft(
    const float2* __restrict__ QKVWs, const ushort_t* __restrict__ Ih,
    float* __restrict__ yout) {
    const int tt = blockIdx.x;   // 0..7
    const int bh = blockIdx.y;   // 0..127
    const int b = bh >> 3, h = bh & 7;
    const int tid = threadIdx.x;
    const int wid = tid >> 6;
    const int lane = tid & 63;
    const int lr = lane & 15;
    const int lg = lane >> 4;

    __shared__ ushort_t Ta[8192];   // table tile: [16 frag][64 lane][8]
    __shared__ unsigned Xs[4096];   // X fp16 pairs, frag order [4ks][4jn][64lane][4]

    const float2* xb = QKVWs + (size_t)bh * 4096;
#pragma unroll
    for (int r = 0; r < 16; ++r) {
        int i = tid + r * 256;
        int x = i >> 6, o = i & 63;
        float2 val = xb[i];
        int ks = x >> 4;
        int lane2 = (((x & 15) >> 2) << 4) | (o & 15);
        int jn = o >> 4;
        unsigned pk = (unsigned)__half_as_ushort(__float2half(val.x)) |
                      ((unsigned)__half_as_ushort(__float2half(val.y)) << 16);
        Xs[((ks * 4 + jn) * 64 + lane2) * 4 + (x & 3)] = pk;
    }
    {
        const ushort_t* gh = Ih + (size_t)(tt * 4) * 8192;
#pragma unroll
        for (int p = 0; p < 4; ++p)
            gld_lds16(gh + (size_t)(tid + p * 256) * 8, &Ta[(tid + p * 256) * 8]);
    }
    __syncthreads();

    f32x4 acc[4][4];
#pragma unroll
    for (int m = 0; m < 4; ++m)
#pragma unroll
        for (int n = 0; n < 4; ++n) acc[m][n] = (f32x4){0.f, 0.f, 0.f, 0.f};

    const ushort_t* XsS = (const ushort_t*)Xs;
    for (int ks = 0; ks < 4; ++ks) {
        half8 ah[4], bx_[4];
#pragma unroll
        for (int m = 0; m < 4; ++m)
            ah[m] = *(const half8*)&Ta[((wid * 4 + m) * 64 + lane) * 8];
#pragma unroll
        for (int n = 0; n < 4; ++n)
            bx_[n] = *(const half8*)&XsS[((ks * 4 + n) * 64 + lane) * 8];
#pragma unroll
        for (int m = 0; m < 4; ++m)
#pragma unroll
            for (int n = 0; n < 4; ++n)
                acc[m][n] = __builtin_amdgcn_mfma_f32_16x16x32_f16(ah[m], bx_[n], acc[m][n], 0, 0, 0);
        if (ks < 3) {
            __syncthreads();
            const ushort_t* gh = Ih + (size_t)(tt * 4 + ks + 1) * 8192;
#pragma unroll
            for (int p = 0; p < 4; ++p)
                gld_lds16(gh + (size_t)(tid + p * 256) * 8, &Ta[(tid + p * 256) * 8]);
            __syncthreads();
        }
    }

    const int t0 = tt * 256 + wid * 64;
    const float inv = 1.f / 1024.f;
#pragma unroll
    for (int m = 0; m < 4; ++m) {
#pragma unroll
        for (int n = 0; n < 4; ++n) {
            const int o = n * 16 + lr;
#pragma unroll
            for (int r = 0; r < 4; ++r) {
                const int t = t0 + m * 16 + lg * 4 + r;
                yout[(((size_t)b * NL + t) * NH + h) * NE + o] = acc[m][n][r] * inv;
            }
        }
    }
}

extern "C" void kernel_launch(void* const* d_in, const int* in_sizes, int n_in,
                              void* d_out, int out_size, void* d_ws, size_t ws_size,
                              hipStream_t stream) {
    const float* q  = (const float*)d_in[0];
    const float* k  = (const float*)d_in[1];
    const float* v  = (const float*)d_in[2];
    const float* wr = (const float*)d_in[3];
    const float* wi = (const float*)d_in[4];
    float* out = (float*)d_out;

    // workspace layout (bytes); Part overlays the post-reduce tail (QKt/QKV/Wt)
    char* w = (char*)d_ws;
    ushort_t* Twh  = (ushort_t*)w;                      //   524,288 B (bf16 hi DFT table)
    ushort_t* Twl  = (ushort_t*)(w + 524288);           //   524,288 B (bf16 lo DFT table)
    ushort_t* Ih   = (ushort_t*)(w + 1048576);          //   524,288 B (fp16 iDFT table)
    float2*   Qf   = (float2*)(w + 2097152);            // 4,194,304 B each below
    float2*   Kf   = (float2*)(w + 6291456);
    float2*   Vf   = (float2*)(w + 10485760);
    float*    Part = (float*)(w + 14680064);            // 25,165,824 B (6 x 1M floats)
    float2*   QKt  = (float2*)(w + 14680064);           // overlays Part (post-reduce)
    float2*   QKV  = (float2*)(w + 18874368);
    float2*   Wt   = (float2*)(w + 23068672);           // 16,777,216 B
    float2*   QKVWs= (float2*)(w + 39845888);           // 4,194,304 B
    // total = 44,040,192 B

    hipLaunchKernelGGL(k_tables_gemm, dim3(1024), dim3(256), 0, stream, Twh, Twl);
    hipLaunchKernelGGL(k_tables_idft, dim3(1024), dim3(256), 0, stream, Ih);
    hipLaunchKernelGGL(k_gemm, dim3(16, 16, 3), dim3(256), 0, stream,
                       q, k, v, Twh, Twl, Part);
    hipLaunchKernelGGL(k_reduce, dim3(3072), dim3(256), 0, stream,
                       (const float4*)Part, (float4*)Qf, (float4*)Kf, (float4*)Vf);
    hipLaunchKernelGGL(k_qk, dim3(128, 2), dim3(256), 0, stream, Qf, Kf, QKt);
    hipLaunchKernelGGL(k_qkv, dim3(128, 2), dim3(256), 0, stream, Vf, QKt, QKV);
    hipLaunchKernelGGL(k_wt, dim3(64, 8), dim3(256), 0, stream, wr, wi, Wt);
    hipLaunchKernelGGL(k_qkvw, dim3(64, 8), dim3(256), 0, stream, QKV, Wt, QKVWs);
    hipLaunchKernelGGL(k_idft, dim3(8, 128), dim3(256), 0, stream, QKVWs, Ih, out);
}

// Round 7
// 150.862 us; speedup vs baseline: 1.5534x; 1.0292x over previous
//
#include <hip/hip_runtime.h>
#include <hip/hip_fp16.h>
#include <math.h>

// FourierCrossAttention: B=16, L=S=2048, H=8, E=O=64, M=64 (first 64 rfft modes)
// Pipeline: tables -> MFMA bf16 3-product DFT(q,k,v) [K-split x2 + reduce] -> QK+tanh
//           -> QKV -> Wt -> QKVW(x1024) -> MFMA fp16 1-product iDFT (/1024)
// DFT v3: A (input) loaded global->reg directly (no LDS round-trip), hi/lo bf16 in-reg;
//         B (table) frag-order in LDS via gld_lds (conflict-free b128), dbuf, 1 barrier pair/2 ksteps.

#define NB 16
#define NL 2048
#define NH 8
#define NE 64
#define NM 64
#define NHE 512  // H*E

typedef unsigned short ushort_t;
typedef __attribute__((ext_vector_type(8))) short short8;
typedef __attribute__((ext_vector_type(8))) _Float16 half8;
typedef __attribute__((ext_vector_type(4))) float f32x4;

__device__ inline void gld_lds16(const void* g, void* l) {
    __builtin_amdgcn_global_load_lds((const __attribute__((address_space(1))) unsigned int*)g,
                                     (__attribute__((address_space(3))) unsigned int*)l, 16, 0, 0);
}

// ---------------- K0a: bf16 hi/lo DFT twiddle tables in MFMA fragment order ----------------
// flat i = ks*4096 + g*512 + l*8 + kj ; mp = g*16 + (l&15), kk = (l>>4)*8 + kj,
// t = ks*32 + kk, m = mp>>1 ; val = (mp odd) ? -sin(2pi m t/L) : cos(2pi m t/L)
__global__ __launch_bounds__(256) void k_tables_gemm(ushort_t* __restrict__ Twh,
                                                     ushort_t* __restrict__ Twl) {
    int i = blockIdx.x * 256 + threadIdx.x;  // over 64*4096 = 262144
    int kj = i & 7;
    int l  = (i >> 3) & 63;
    int g  = (i >> 9) & 7;
    int ks = i >> 12;
    int mp = g * 16 + (l & 15);
    int kk = (l >> 4) * 8 + kj;
    int t = ks * 32 + kk;
    int m = mp >> 1;
    float ang = (float)((6.283185307179586476925287 / (double)NL) * (double)((m * t) & (NL - 1)));
    float val = (mp & 1) ? -sinf(ang) : cosf(ang);
    unsigned cb = __float_as_uint(val);
    ushort_t h = (ushort_t)(cb >> 16);
    float lo = val - __uint_as_float(cb & 0xffff0000u);
    unsigned lb = __float_as_uint(lo);
    unsigned r = lb + 0x7fffu + ((lb >> 16) & 1u);
    Twh[i] = h;
    Twl[i] = (ushort_t)(r >> 16);
}

// ---------------- K0b: fp16 iDFT twiddle in MFMA fragment order ----------------
__global__ __launch_bounds__(256) void k_tables_idft(ushort_t* __restrict__ Ih) {
    int i = blockIdx.x * 256 + threadIdx.x;  // over 262144
    int j = i & 7;
    int l = (i >> 3) & 63;
    int f = (i >> 9) & 15;
    int ks = (i >> 13) & 3;
    int tt = i >> 15;
    int t = tt * 256 + f * 16 + (l & 15);
    int kk = ks * 32 + (l >> 4) * 8 + j;
    int x = kk >> 1;
    float ang = (float)((6.283185307179586476925287 / (double)NL) * (double)((t * x) & (NL - 1)));
    float val = (kk & 1) ? -sinf(ang) : cosf(ang);
    Ih[i] = __half_as_ushort(__float2half(val));
}

// ---------------- K1: MFMA bf16 3-product DFT v3 (A reg-direct), K-split x2 ----------------
// Cpart[he, m'] = sum_t X[t, he] * Tw[t, m'] per (b, z, kq). Block 128he x 128m',
// 4 waves stacked on he (wave tile 32he x 128m'), BK=32, 32 iters per K-half.
// A: global->reg (coalesced 64B segments, each element read once); convert hi/lo in reg.
// B: frag-order bf16 hi/lo via gld_lds, double-buffered, conflict-free ds_read_b128.
__global__ __launch_bounds__(256, 3) void k_gemm(
    const float* __restrict__ q, const float* __restrict__ k, const float* __restrict__ v,
    const ushort_t* __restrict__ Twh, const ushort_t* __restrict__ Twl,
    float* __restrict__ Part) {
    const int bx = blockIdx.x & 3;   // he-group 0..3 (128 each)
    const int kq = blockIdx.x >> 2;  // K-half 0..1
    const int b  = blockIdx.y;       // 0..15
    const int z  = blockIdx.z;       // 0..2
    const float* __restrict__ in = (z == 0) ? q : ((z == 1) ? k : v);

    const int tid  = threadIdx.x;
    const int wid  = tid >> 6;       // he-block within tile (0..3)
    const int lane = tid & 63;
    const int lr   = lane & 15;
    const int lg   = lane >> 4;

    __shared__ ushort_t Bh[2][4096];  // frag-order bf16 hi, 8 KB each
    __shared__ ushort_t Bl[2][4096];  // frag-order bf16 lo, 8 KB each

    f32x4 acc[2][8];
#pragma unroll
    for (int f = 0; f < 2; ++f)
#pragma unroll
        for (int g = 0; g < 8; ++g) acc[f][g] = (f32x4){0.f, 0.f, 0.f, 0.f};

    // per-lane A base: he = bx*128 + wid*32 + f*16 + lr ; t = kq*1024 + ks*32 + lg*8 + j
    const float* pA = in + ((size_t)b * NL + (size_t)kq * 1024) * NHE + bx * 128 + wid * 32 + lr;

    float arE[2][8], arO[2][8];

#define STAGE_B(n, ksn)                                                               \
    {                                                                                 \
        const ushort_t* gh = Twh + (size_t)(kq * 32 + (ksn)) * 4096;                  \
        const ushort_t* gl = Twl + (size_t)(kq * 32 + (ksn)) * 4096;                  \
        gld_lds16(gh + (size_t)tid * 8, &Bh[n][tid * 8]);                             \
        gld_lds16(gh + (size_t)(tid + 256) * 8, &Bh[n][(tid + 256) * 8]);             \
        gld_lds16(gl + (size_t)tid * 8, &Bl[n][tid * 8]);                             \
        gld_lds16(gl + (size_t)(tid + 256) * 8, &Bl[n][(tid + 256) * 8]);             \
    }

#define LOADA(ar, ksn)                                                                \
    {                                                                                 \
        _Pragma("unroll")                                                             \
        for (int f = 0; f < 2; ++f) {                                                 \
            _Pragma("unroll")                                                         \
            for (int j = 0; j < 8; ++j)                                               \
                ar[f][j] = pA[(size_t)((ksn) * 32 + lg * 8 + j) * NHE + f * 16];      \
        }                                                                             \
    }

#define COMPUTE(ar, n)                                                                \
    {                                                                                 \
        short8 ah[2], al[2];                                                          \
        _Pragma("unroll")                                                             \
        for (int f = 0; f < 2; ++f) {                                                 \
            union { unsigned u[4]; short8 s; } uh, ul;                                \
            _Pragma("unroll")                                                         \
            for (int p = 0; p < 4; ++p) {                                             \
                unsigned b0 = __float_as_uint(ar[f][2 * p]);                          \
                unsigned b1 = __float_as_uint(ar[f][2 * p + 1]);                      \
                uh.u[p] = (b0 >> 16) | (b1 & 0xffff0000u);                            \
                float l0 = ar[f][2 * p]     - __uint_as_float(b0 & 0xffff0000u);      \
                float l1 = ar[f][2 * p + 1] - __uint_as_float(b1 & 0xffff0000u);      \
                unsigned lw;                                                          \
                asm("v_cvt_pk_bf16_f32 %0, %1, %2" : "=v"(lw) : "v"(l0), "v"(l1));    \
                ul.u[p] = lw;                                                         \
            }                                                                         \
            ah[f] = uh.s; al[f] = ul.s;                                               \
        }                                                                             \
        _Pragma("unroll")                                                             \
        for (int g = 0; g < 8; ++g) {                                                 \
            short8 bh8 = *(const short8*)&Bh[n][(g * 64 + lane) * 8];                 \
            short8 bl8 = *(const short8*)&Bl[n][(g * 64 + lane) * 8];                 \
            _Pragma("unroll")                                                         \
            for (int f = 0; f < 2; ++f) {                                             \
                acc[f][g] = __builtin_amdgcn_mfma_f32_16x16x32_bf16(ah[f], bh8, acc[f][g], 0, 0, 0); \
                acc[f][g] = __builtin_amdgcn_mfma_f32_16x16x32_bf16(al[f], bh8, acc[f][g], 0, 0, 0); \
                acc[f][g] = __builtin_amdgcn_mfma_f32_16x16x32_bf16(ah[f], bl8, acc[f][g], 0, 0, 0); \
            }                                                                         \
        }                                                                             \
    }

    // prologue
    STAGE_B(0, 0);
    LOADA(arE, 0);

    // 32 iterations, double-body for static reg parity
#pragma unroll 1
    for (int k2 = 0; k2 < 16; ++k2) {
        const int ksB = 2 * k2 + 1;
        __syncthreads();                 // Bh/Bl[0] ready (and prior A-loads drained)
        STAGE_B(1, ksB);
        LOADA(arO, ksB);
        COMPUTE(arE, 0);
        __syncthreads();                 // Bh/Bl[1] ready
        if (k2 < 15) {
            STAGE_B(0, ksB + 1);
            LOADA(arE, ksB + 1);
        }
        COMPUTE(arO, 1);
    }
#undef STAGE_B
#undef LOADA
#undef COMPUTE

    // ---- epilogue: Part[(z*2+kq)][(b*512+he)][m'] (layout identical to R6) ----
    float* pout = Part + (size_t)(z * 2 + kq) * 1048576;
#pragma unroll
    for (int f = 0; f < 2; ++f) {
#pragma unroll
        for (int g = 0; g < 8; ++g) {
            const int col = g * 16 + lr;
#pragma unroll
            for (int r = 0; r < 4; ++r) {
                const int he = bx * 128 + wid * 32 + f * 16 + 4 * lg + r;
                pout[((size_t)b * NHE + he) * 128 + col] = acc[f][g][r];
            }
        }
    }
}

// ---------------- K1b: reduce 2 K-half partials -> Qf/Kf/Vf ----------------
__global__ __launch_bounds__(256) void k_reduce(
    const float4* __restrict__ Part, float4* __restrict__ Qf,
    float4* __restrict__ Kf, float4* __restrict__ Vf) {
    int i = blockIdx.x * 256 + threadIdx.x;  // over 3*262144
    int z = i >> 18;
    int r = i & 262143;
    float4 a = Part[(size_t)(z * 2 + 0) * 262144 + r];
    float4 b = Part[(size_t)(z * 2 + 1) * 262144 + r];
    float4 s = make_float4(a.x + b.x, a.y + b.y, a.z + b.z, a.w + b.w);
    float4* o = (z == 0) ? Qf : ((z == 1) ? Kf : Vf);
    o[r] = s;
}

// ---------------- K2: QK = sum_e Qf[e,x]*Kf[e,y]; tanh re/im ----------------
__global__ __launch_bounds__(256) void k_qk(
    const float2* __restrict__ Qf, const float2* __restrict__ Kf,
    float2* __restrict__ QKt) {
    const int bh = blockIdx.x;  // 0..127
    const int xh = blockIdx.y;  // 0..1
    const int tid = threadIdx.x;
    __shared__ float2 Qs[64 * 34];
    __shared__ float2 Ks[64 * 66];

    const float2* Qbase = Qf + (size_t)bh * (NE * NM);
    const float2* Kbase = Kf + (size_t)bh * (NE * NM);
#pragma unroll
    for (int j = 0; j < 4; ++j) {
        int n = tid + j * 256;  // 1024 f4
        int e = n >> 4, c = n & 15;
        float4 val = ((const float4*)(Qbase + e * NM + xh * 32))[c];
        *((float4*)&Qs[e * 34 + c * 2]) = val;
    }
#pragma unroll
    for (int j = 0; j < 8; ++j) {
        int n = tid + j * 256;  // 2048 f4
        int e = n >> 5, c = n & 31;
        float4 val = ((const float4*)(Kbase + e * NM))[c];
        *((float4*)&Ks[e * 66 + c * 2]) = val;
    }
    __syncthreads();

    const int yq = tid & 31, xq = tid >> 5;
    float accr[4][2], acci[4][2];
#pragma unroll
    for (int i = 0; i < 4; ++i)
#pragma unroll
        for (int j = 0; j < 2; ++j) { accr[i][j] = 0.f; acci[i][j] = 0.f; }

    for (int e = 0; e < 64; ++e) {
        float4 qa = *((float4*)&Qs[e * 34 + xq * 4]);
        float4 qb = *((float4*)&Qs[e * 34 + xq * 4 + 2]);
        float4 kk = *((float4*)&Ks[e * 66 + yq * 2]);
        float qr[4] = {qa.x, qa.z, qb.x, qb.z};
        float qi[4] = {qa.y, qa.w, qb.y, qb.w};
        float kr[2] = {kk.x, kk.z};
        float ki[2] = {kk.y, kk.w};
#pragma unroll
        for (int i = 0; i < 4; ++i) {
#pragma unroll
            for (int j = 0; j < 2; ++j) {
                accr[i][j] += qr[i] * kr[j] - qi[i] * ki[j];
                acci[i][j] += qr[i] * ki[j] + qi[i] * kr[j];
            }
        }
    }
    const int x0 = xh * 32 + xq * 4;
#pragma unroll
    for (int i = 0; i < 4; ++i) {
        float4 sv = make_float4(tanhf(accr[i][0]), tanhf(acci[i][0]),
                                tanhf(accr[i][1]), tanhf(acci[i][1]));
        *((float4*)&QKt[(size_t)bh * 4096 + (x0 + i) * 64 + yq * 2]) = sv;
    }
}

// ---------------- K3: QKV[e,x] = sum_y Vf[e,y]*QKt[x,y] ----------------
__global__ __launch_bounds__(256) void k_qkv(
    const float2* __restrict__ Vf, const float2* __restrict__ QKt,
    float2* __restrict__ QKV) {
    const int bh = blockIdx.x;
    const int eh = blockIdx.y;
    const int tid = threadIdx.x;
    __shared__ float2 Vs[32 * 66];
    __shared__ float2 Ps[64 * 66];

    const float2* Vbase = Vf + (size_t)bh * (NE * NM) + eh * 32 * NM;
    const float2* Pbase = QKt + (size_t)bh * 4096;
#pragma unroll
    for (int j = 0; j < 4; ++j) {
        int n = tid + j * 256;
        int r = n >> 5, c = n & 31;
        float4 val = ((const float4*)(Vbase + r * NM))[c];
        *((float4*)&Vs[r * 66 + c * 2]) = val;
    }
#pragma unroll
    for (int j = 0; j < 8; ++j) {
        int n = tid + j * 256;
        int r = n >> 5, c = n & 31;
        float4 val = ((const float4*)(Pbase + r * NM))[c];
        *((float4*)&Ps[r * 66 + c * 2]) = val;
    }
    __syncthreads();

    const int xq = tid & 15, eq2 = tid >> 4;
    const int x0 = xq * 4, e0 = eq2 * 2;
    float accr[2][4], acci[2][4];
#pragma unroll
    for (int i = 0; i < 2; ++i)
#pragma unroll
        for (int j = 0; j < 4; ++j) { accr[i][j] = 0.f; acci[i][j] = 0.f; }

    for (int yy = 0; yy < 64; ++yy) {
        float2 v0 = Vs[(e0 + 0) * 66 + yy];
        float2 v1 = Vs[(e0 + 1) * 66 + yy];
        float2 p0 = Ps[(x0 + 0) * 66 + yy];
        float2 p1 = Ps[(x0 + 1) * 66 + yy];
        float2 p2 = Ps[(x0 + 2) * 66 + yy];
        float2 p3 = Ps[(x0 + 3) * 66 + yy];
        float pr[4] = {p0.x, p1.x, p2.x, p3.x};
        float pi[4] = {p0.y, p1.y, p2.y, p3.y};
#pragma unroll
        for (int j = 0; j < 4; ++j) {
            accr[0][j] += v0.x * pr[j] - v0.y * pi[j];
            acci[0][j] += v0.x * pi[j] + v0.y * pr[j];
            accr[1][j] += v1.x * pr[j] - v1.y * pi[j];
            acci[1][j] += v1.x * pi[j] + v1.y * pr[j];
        }
    }
#pragma unroll
    for (int e = 0; e < 2; ++e) {
        float2* obase = QKV + (size_t)bh * 4096 + (eh * 32 + e0 + e) * 64 + x0;
        float4 s0 = make_float4(accr[e][0], acci[e][0], accr[e][1], acci[e][1]);
        float4 s1 = make_float4(accr[e][2], acci[e][2], accr[e][3], acci[e][3]);
        ((float4*)obase)[0] = s0;
        ((float4*)obase)[1] = s1;
    }
}

// ---------------- K4a: transpose W -> Wt[h][x][e][o] ----------------
__global__ __launch_bounds__(256) void k_wt(
    const float* __restrict__ wr, const float* __restrict__ wi,
    float2* __restrict__ Wt) {
    const int e = blockIdx.x, h = blockIdx.y;
    const int tid = threadIdx.x;
    __shared__ float lr[64 * 68];
    __shared__ float li[64 * 68];
    const float* rbase = wr + (size_t)(h * NE + e) * NE * NM;
    const float* ibase = wi + (size_t)(h * NE + e) * NE * NM;
#pragma unroll
    for (int j = 0; j < 4; ++j) {
        int n = tid + j * 256;
        int o = n >> 4, x4 = n & 15;
        float4 r4 = ((const float4*)(rbase + o * NM))[x4];
        float4 i4 = ((const float4*)(ibase + o * NM))[x4];
        *((float4*)&lr[o * 68 + x4 * 4]) = r4;
        *((float4*)&li[o * 68 + x4 * 4]) = i4;
    }
    __syncthreads();
#pragma unroll
    for (int j = 0; j < 16; ++j) {
        int n = tid + j * 256;
        int x = n >> 6, o = n & 63;
        Wt[((size_t)(h * NM + x) * NE + e) * NE + o] =
            make_float2(lr[o * 68 + x], li[o * 68 + x]);
    }
}

// ---------------- K4: QKVW[o,x] = sum_e QKV[e,x]*W[e,o,x], irfft scale x1024 ----------------
__global__ __launch_bounds__(256) void k_qkvw(
    const float2* __restrict__ QKV, const float2* __restrict__ Wt,
    float2* __restrict__ QKVWs) {
    const int x = blockIdx.x, h = blockIdx.y;
    const int tid = threadIdx.x;
    const int o = tid & 63, bq = tid >> 6;
    float accr[4], acci[4];
#pragma unroll
    for (int j = 0; j < 4; ++j) { accr[j] = 0.f; acci[j] = 0.f; }

    const float2* wbase = Wt + (size_t)(h * NM + x) * NE * NE + o;
    for (int e = 0; e < 64; ++e) {
        float2 w = wbase[(size_t)e * NE];
#pragma unroll
        for (int j = 0; j < 4; ++j) {
            int b = bq * 4 + j;
            float2 a = QKV[((size_t)(b * NH + h) * NE + e) * NM + x];
            accr[j] += a.x * w.x - a.y * w.y;
            acci[j] += a.x * w.y + a.y * w.x;
        }
    }
    // (1/NL or 2/NL) * 1024 (exact powers of 2); undone by /1024 in k_idft epilogue
    const float sc = (x == 0) ? 0.5f : 1.0f;
#pragma unroll
    for (int j = 0; j < 4; ++j) {
        int b = bq * 4 + j;
        QKVWs[((size_t)(b * NH + h) * NM + x) * NE + o] =
            make_float2(accr[j] * sc, acci[j] * sc);
    }
}

// ---------------- K5: MFMA fp16 1-product iDFT + transpose to [B,L,H,O] ----------------
__global__ __launch_bounds__(256, 3) void k_idft(
    const float2* __restrict__ QKVWs, const ushort_t* __restrict__ Ih,
    float* __restrict__ yout) {
    const int tt = blockIdx.x;   // 0..7
    const int bh = blockIdx.y;   // 0..127
    const int b = bh >> 3, h = bh & 7;
    const int tid = threadIdx.x;
    const int wid = tid >> 6;
    const int lane = tid & 63;
    const int lr = lane & 15;
    const int lg = lane >> 4;

    __shared__ ushort_t Ta[8192];   // table tile: [16 frag][64 lane][8]
    __shared__ unsigned Xs[4096];   // X fp16 pairs, frag order [4ks][4jn][64lane][4]

    const float2* xb = QKVWs + (size_t)bh * 4096;
#pragma unroll
    for (int r = 0; r < 16; ++r) {
        int i = tid + r * 256;
        int x = i >> 6, o = i & 63;
        float2 val = xb[i];
        int ks = x >> 4;
        int lane2 = (((x & 15) >> 2) << 4) | (o & 15);
        int jn = o >> 4;
        unsigned pk = (unsigned)__half_as_ushort(__float2half(val.x)) |
                      ((unsigned)__half_as_ushort(__float2half(val.y)) << 16);
        Xs[((ks * 4 + jn) * 64 + lane2) * 4 + (x & 3)] = pk;
    }
    {
        const ushort_t* gh = Ih + (size_t)(tt * 4) * 8192;
#pragma unroll
        for (int p = 0; p < 4; ++p)
            gld_lds16(gh + (size_t)(tid + p * 256) * 8, &Ta[(tid + p * 256) * 8]);
    }
    __syncthreads();

    f32x4 acc[4][4];
#pragma unroll
    for (int m = 0; m < 4; ++m)
#pragma unroll
        for (int n = 0; n < 4; ++n) acc[m][n] = (f32x4){0.f, 0.f, 0.f, 0.f};

    const ushort_t* XsS = (const ushort_t*)Xs;
    for (int ks = 0; ks < 4; ++ks) {
        half8 ah[4], bx_[4];
#pragma unroll
        for (int m = 0; m < 4; ++m)
            ah[m] = *(const half8*)&Ta[((wid * 4 + m) * 64 + lane) * 8];
#pragma unroll
        for (int n = 0; n < 4; ++n)
            bx_[n] = *(const half8*)&XsS[((ks * 4 + n) * 64 + lane) * 8];
#pragma unroll
        for (int m = 0; m < 4; ++m)
#pragma unroll
            for (int n = 0; n < 4; ++n)
                acc[m][n] = __builtin_amdgcn_mfma_f32_16x16x32_f16(ah[m], bx_[n], acc[m][n], 0, 0, 0);
        if (ks < 3) {
            __syncthreads();
            const ushort_t* gh = Ih + (size_t)(tt * 4 + ks + 1) * 8192;
#pragma unroll
            for (int p = 0; p < 4; ++p)
                gld_lds16(gh + (size_t)(tid + p * 256) * 8, &Ta[(tid + p * 256) * 8]);
            __syncthreads();
        }
    }

    const int t0 = tt * 256 + wid * 64;
    const float inv = 1.f / 1024.f;
#pragma unroll
    for (int m = 0; m < 4; ++m) {
#pragma unroll
        for (int n = 0; n < 4; ++n) {
            const int o = n * 16 + lr;
#pragma unroll
            for (int r = 0; r < 4; ++r) {
                const int t = t0 + m * 16 + lg * 4 + r;
                yout[(((size_t)b * NL + t) * NH + h) * NE + o] = acc[m][n][r] * inv;
            }
        }
    }
}

extern "C" void kernel_launch(void* const* d_in, const int* in_sizes, int n_in,
                              void* d_out, int out_size, void* d_ws, size_t ws_size,
                              hipStream_t stream) {
    const float* q  = (const float*)d_in[0];
    const float* k  = (const float*)d_in[1];
    const float* v  = (const float*)d_in[2];
    const float* wr = (const float*)d_in[3];
    const float* wi = (const float*)d_in[4];
    float* out = (float*)d_out;

    // workspace layout (bytes); Part overlays the post-reduce tail (QKt/QKV/Wt)
    char* w = (char*)d_ws;
    ushort_t* Twh  = (ushort_t*)w;                      //   524,288 B (bf16 hi DFT table)
    ushort_t* Twl  = (ushort_t*)(w + 524288);           //   524,288 B (bf16 lo DFT table)
    ushort_t* Ih   = (ushort_t*)(w + 1048576);          //   524,288 B (fp16 iDFT table)
    float2*   Qf   = (float2*)(w + 2097152);            // 4,194,304 B each below
    float2*   Kf   = (float2*)(w + 6291456);
    float2*   Vf   = (float2*)(w + 10485760);
    float*    Part = (float*)(w + 14680064);            // 25,165,824 B (6 x 1M floats)
    float2*   QKt  = (float2*)(w + 14680064);           // overlays Part (post-reduce)
    float2*   QKV  = (float2*)(w + 18874368);
    float2*   Wt   = (float2*)(w + 23068672);           // 16,777,216 B
    float2*   QKVWs= (float2*)(w + 39845888);           // 4,194,304 B
    // total = 44,040,192 B

    hipLaunchKernelGGL(k_tables_gemm, dim3(1024), dim3(256), 0, stream, Twh, Twl);
    hipLaunchKernelGGL(k_tables_idft, dim3(1024), dim3(256), 0, stream, Ih);
    hipLaunchKernelGGL(k_gemm, dim3(8, 16, 3), dim3(256), 0, stream,
                       q, k, v, Twh, Twl, Part);
    hipLaunchKernelGGL(k_reduce, dim3(3072), dim3(256), 0, stream,
                       (const float4*)Part, (float4*)Qf, (float4*)Kf, (float4*)Vf);
    hipLaunchKernelGGL(k_qk, dim3(128, 2), dim3(256), 0, stream, Qf, Kf, QKt);
    hipLaunchKernelGGL(k_qkv, dim3(128, 2), dim3(256), 0, stream, Vf, QKt, QKV);
    hipLaunchKernelGGL(k_wt, dim3(64, 8), dim3(256), 0, stream, wr, wi, Wt);
    hipLaunchKernelGGL(k_qkvw, dim3(64, 8), dim3(256), 0, stream, QKV, Wt, QKVWs);
    hipLaunchKernelGGL(k_idft, dim3(8, 128), dim3(256), 0, stream, QKVWs, Ih, out);
}